// Round 14
// baseline (573.238 us; speedup 1.0000x reference)
//
#include <hip/hip_runtime.h>
#include <hip/hip_bf16.h>
#include <cstdint>
#include <cstddef>
#include <type_traits>

#define NN 8192
#define NTYPE 6
#define BPT 32  // histogram/scatter slices per (type, role)

typedef __attribute__((ext_vector_type(8))) short bf16x8;
typedef __attribute__((ext_vector_type(4))) float f32x4;
typedef __attribute__((ext_vector_type(4))) unsigned short u16x4;
typedef __attribute__((ext_vector_type(8))) unsigned short u16x8;

#define GLOAD16(g, l)                                                        \
  __builtin_amdgcn_global_load_lds(                                          \
      (const __attribute__((address_space(1))) void*)(g),                    \
      (__attribute__((address_space(3))) void*)(l), 16, 0, 0)

static __device__ __forceinline__ unsigned short f2bf(float f) {
  union { float f; unsigned u; } x; x.f = f;
  unsigned u = x.u + 0x7fffu + ((x.u >> 16) & 1u);
  return (unsigned short)(u >> 16);
}
static __device__ __forceinline__ float bf2f(unsigned short u) {
  union { unsigned u32; float f; } x; x.u32 = (unsigned)u << 16; return x.f;
}

// ---------------- degree histograms: LDS-privatized, non-atomic flush ----------------
__global__ __launch_bounds__(256) void hist_degree(
    const int* __restrict__ edges, int* __restrict__ partial, int E) {
  const int b = blockIdx.x, t = blockIdx.y, role = blockIdx.z;
  __shared__ int h[NN];
  for (int i = threadIdx.x; i < NN; i += 256) h[i] = 0;
  __syncthreads();
  const int* ids = edges + ((size_t)t * 2 + role) * E;
  int ch = (E + BPT - 1) / BPT;
  int beg = b * ch, end = (beg + ch < E) ? beg + ch : E;
  for (int i = beg + threadIdx.x; i < end; i += 256)
    atomicAdd(&h[__builtin_nontemporal_load(ids + i)], 1);
  __syncthreads();
  int* dst = partial + ((size_t)((role * NTYPE + t) * BPT + b)) * NN;
  for (int i = threadIdx.x; i < NN; i += 256) dst[i] = h[i];
}

// ---------------- fused: reduce degrees + scan + slice offsets (1 block/type) ----
__global__ __launch_bounds__(1024) void build_offsets(
    const int* __restrict__ partial, float* __restrict__ inv_out,
    float* __restrict__ inv_in, int* __restrict__ row_start,
    int* __restrict__ soff) {
  const int t = blockIdx.x, i = threadIdx.x;
  const int* ps = partial + (size_t)(t * BPT) * NN;
  const int* pd = partial + (size_t)((NTYPE + t) * BPT) * NN;
  // outdeg -> inv_out (coalesced over d)
  for (int d = i; d < NN; d += 1024) {
    int so = 0;
#pragma unroll 8
    for (int b = 0; b < BPT; ++b) so += ps[(size_t)b * NN + d];
    inv_out[t * NN + d] = rsqrtf(fmaxf((float)so, 1.0f));
  }
  // indeg sums (d = i*8+j layout for the scan)
  int v[8], s = 0;
#pragma unroll
  for (int j = 0; j < 8; ++j) {
    int d = i * 8 + j;
    int sd = 0;
#pragma unroll 8
    for (int b = 0; b < BPT; ++b) sd += pd[(size_t)b * NN + d];
    v[j] = sd; s += sd;
    inv_in[t * NN + d] = rsqrtf(fmaxf((float)sd, 1.0f));
  }
  __shared__ int p[1024];
  p[i] = s;
  __syncthreads();
  for (int dd = 1; dd < 1024; dd <<= 1) {
    int x = (i >= dd) ? p[i - dd] : 0;
    __syncthreads();
    p[i] += x;
    __syncthreads();
  }
  int run = p[i] - s;
  int* rs = row_start + t * (NN + 1);
#pragma unroll
  for (int j = 0; j < 8; ++j) { rs[i * 8 + j] = run; run += v[j]; }
  if (i == 1023) rs[NN] = run;
  __syncthreads();
  // slice offsets (coalesced over d)
  int* o = soff + (size_t)t * BPT * NN;
  for (int d = i; d < NN; d += 1024) {
    int r2 = rs[d];
#pragma unroll 8
    for (int sl = 0; sl < BPT; ++sl) {
      o[(size_t)sl * NN + d] = r2;
      r2 += pd[(size_t)sl * NN + d];
    }
  }
}

// atomic-free scatter: LDS cursors seeded from soff; grid (8, BPT), x = type
__global__ __launch_bounds__(256) void scatter_v2(
    const int* __restrict__ edges, const int* __restrict__ soff,
    int* __restrict__ csr, int E) {
  int t = blockIdx.x;
  if (t >= NTYPE) return;
  int s = blockIdx.y;
  __shared__ int cur[NN];
  const int* o = soff + ((size_t)(t * BPT + s)) * NN;
  for (int i = threadIdx.x; i < NN; i += 256) cur[i] = o[i];
  __syncthreads();
  int ch = (E + BPT - 1) / BPT;
  int beg = s * ch, end = (beg + ch < E) ? beg + ch : E;
  const int* eb = edges + (size_t)t * 2 * E;
  int* out = csr + (size_t)t * E;
  for (int i = beg + threadIdx.x; i < end; i += 256) {
    int src = __builtin_nontemporal_load(eb + i);
    int dst = __builtin_nontemporal_load(eb + E + i);
    int pos = atomicAdd(&cur[dst], 1);
    out[pos] = src;
  }
}

// ---------------- batched 64x64 fp32 GEMM for GNN xs, bf16 out ----------------
// tpack: 4-bit packed list of active edge types, indexed by blockIdx.z.
__global__ __launch_bounds__(256) void gemm64xs(
    const float* __restrict__ p0, const float* __restrict__ p1,
    const float* __restrict__ p2, int lda,
    const float* __restrict__ WL, const float* __restrict__ inv_out,
    unsigned short* __restrict__ xs6, int F, int H, int tpack) {
  const int t = (tpack >> (4 * blockIdx.z)) & 15;
  const int srcc[6] = {0, 1, 0, 2, 2, 1};
  const float* A = (srcc[t] == 0) ? p0 : (srcc[t] == 1) ? p1 : p2;
  const float* B = WL + (size_t)t * F * H;  // (F,H) row-major, ldb=H
  const float* rscale = inv_out + t * NN;
  unsigned short* out = xs6 + (size_t)t * NN * H;

  __shared__ float As[16][68];
  __shared__ float Bs[16][68];
  int tid = threadIdx.x;
  int n0 = blockIdx.x * 64, m0 = blockIdx.y * 64;
  int ar = tid >> 2, ac = (tid & 3) * 4;
  int br = tid >> 4, bc = (tid & 15) * 4;
  int tx = tid & 15, ty = tid >> 4;
  float acc[4][4] = {};
  for (int k0 = 0; k0 < F; k0 += 16) {
    float4 av = *(const float4*)(A + (size_t)(m0 + ar) * lda + k0 + ac);
    As[ac + 0][ar] = av.x; As[ac + 1][ar] = av.y;
    As[ac + 2][ar] = av.z; As[ac + 3][ar] = av.w;
    *(float4*)&Bs[br][bc] = *(const float4*)(B + (size_t)(k0 + br) * H + n0 + bc);
    __syncthreads();
#pragma unroll
    for (int kk = 0; kk < 16; ++kk) {
      float4 a = *(const float4*)&As[kk][ty * 4];
      float4 b = *(const float4*)&Bs[kk][tx * 4];
      float aa[4] = {a.x, a.y, a.z, a.w};
      float bb[4] = {b.x, b.y, b.z, b.w};
#pragma unroll
      for (int i = 0; i < 4; ++i)
#pragma unroll
        for (int j = 0; j < 4; ++j) acc[i][j] += aa[i] * bb[j];
    }
    __syncthreads();
  }
#pragma unroll
  for (int i = 0; i < 4; ++i) {
    int r = m0 + ty * 4 + i;
    float sc = rscale[r];
    union { unsigned short us[4]; short4 v; } pk;
#pragma unroll
    for (int j = 0; j < 4; ++j) pk.us[j] = f2bf(acc[i][j] * sc);
    *(short4*)&out[(size_t)r * H + n0 + tx * 4] = pk.v;
  }
}

// ---------------- CSR aggregation v3: 4 edges/VMEM-instr vectorized gather ----
// cpack: 8-bit packed list of active target classes, indexed by blockIdx.y.
// dbase: optional device scalar added to the target-row index (dependency-cone
// prune: the final layer only needs rows [leftIndex, leftIndex+4096)).
template <int H>
__global__ __launch_bounds__(256) void aggregate3(
    const unsigned short* __restrict__ xs6, const int* __restrict__ csr,
    const int* __restrict__ row_start, const float* __restrict__ inv_in,
    const float* __restrict__ bL, float* __restrict__ feat_out, int E, int cpack,
    const int* __restrict__ dbase) {
  constexpr int VE = H / 16;
  const int c = (cpack >> (8 * blockIdx.y)) & 0xff;
  const int taT[3] = {1, 0, 2}, tbT[3] = {3, 4, 5};
  int wave = threadIdx.x >> 6, lane = threadIdx.x & 63;
  int slot = lane >> 4, colg = lane & 15;
  int d = blockIdx.x * 4 + wave;
  if (dbase) d += dbase[0];

  float out[VE];
#pragma unroll
  for (int v = 0; v < VE; ++v) out[v] = 0.f;

#pragma unroll
  for (int half = 0; half < 2; ++half) {
    int t = half ? tbT[c] : taT[c];
    const unsigned short* xs = xs6 + (size_t)t * NN * H;
    const int* cs = csr + (size_t)t * E;
    const int* rs = row_start + t * (NN + 1);
    int b = rs[d], e = rs[d + 1];
    float a[VE];
#pragma unroll
    for (int v = 0; v < VE; ++v) a[v] = 0.f;
    for (int j0 = b; j0 < e; j0 += 64) {
      int myj = j0 + lane;
      int idxv = (myj < e) ? cs[myj] : 0;
      int cnt = e - j0; if (cnt > 64) cnt = 64;
      int g = 0;
      for (; (g + 1) * 4 <= cnt; ++g) {
        int is = __shfl(idxv, g * 4 + slot);
        const unsigned short* xr = xs + (size_t)is * H + colg * VE;
        if constexpr (VE == 4) {
          u16x4 x = *(const u16x4*)xr;
#pragma unroll
          for (int v = 0; v < 4; ++v) a[v] += bf2f(x[v]);
        } else {
          u16x8 x = *(const u16x8*)xr;
#pragma unroll
          for (int v = 0; v < 8; ++v) a[v] += bf2f(x[v]);
        }
      }
      int done = g * 4;
      if (done < cnt) {
        int gi = done + slot;
        int is = __shfl(idxv, gi < cnt ? gi : 0);
        float wt = (gi < cnt) ? 1.0f : 0.0f;
        const unsigned short* xr = xs + (size_t)is * H + colg * VE;
        if constexpr (VE == 4) {
          u16x4 x = *(const u16x4*)xr;
#pragma unroll
          for (int v = 0; v < 4; ++v) a[v] += wt * bf2f(x[v]);
        } else {
          u16x8 x = *(const u16x8*)xr;
#pragma unroll
          for (int v = 0; v < 8; ++v) a[v] += wt * bf2f(x[v]);
        }
      }
    }
    float sc = inv_in[t * NN + d];
#pragma unroll
    for (int v = 0; v < VE; ++v) out[v] += a[v] * sc;
  }
#pragma unroll
  for (int v = 0; v < VE; ++v) {
    out[v] += __shfl_xor(out[v], 16);
    out[v] += __shfl_xor(out[v], 32);
  }
  if (lane < 16) {
    int ta = taT[c], tb = tbT[c];
    float* o = feat_out + (size_t)c * NN * 128 + (size_t)d * H + colg * VE;
    const float* ba = bL + ta * H + colg * VE;
    const float* bb = bL + tb * H + colg * VE;
    float4 w0 = make_float4(out[0] + ba[0] + bb[0], out[1] + ba[1] + bb[1],
                            out[2] + ba[2] + bb[2], out[3] + ba[3] + bb[3]);
    *(float4*)o = w0;
    if constexpr (VE == 8) {
      float4 w1 = make_float4(out[4] + ba[4] + bb[4], out[5] + ba[5] + bb[5],
                              out[6] + ba[6] + bb[6], out[7] + ba[7] + bb[7]);
      *(float4*)(o + 4) = w1;
    }
  }
}

// ---------------- row L1-normalize hM3 -> fake (fp32, to d_out) ----------------
__global__ __launch_bounds__(256) void l1norm_fake(
    const float* __restrict__ hM3, const int* __restrict__ leftIndex,
    float* __restrict__ fake) {
  int wave = threadIdx.x >> 6, lane = threadIdx.x & 63;
  int r = blockIdx.x * 4 + wave;
  int row = leftIndex[0] + r;
  const float* x = hM3 + (size_t)row * 128;
  float a = x[lane], b = x[64 + lane];
  float s = fabsf(a) + fabsf(b);
#pragma unroll
  for (int d = 1; d < 64; d <<= 1) s += __shfl_xor(s, d);
  float inv = 1.0f / fmaxf(s, 1e-12f);
  fake[(size_t)r * 128 + lane]      = a * inv;
  fake[(size_t)r * 128 + 64 + lane] = b * inv;
}

// ---------------- fused cast + transpose fp32 (K,N) -> bf16 (N,K), 4 weights ----
__global__ __launch_bounds__(256) void castT4(
    const float* __restrict__ i0, unsigned short* __restrict__ o0,
    const float* __restrict__ i1, unsigned short* __restrict__ o1,
    const float* __restrict__ i2, unsigned short* __restrict__ o2,
    const float* __restrict__ i3, unsigned short* __restrict__ o3) {
  // segments (K, N): (8320,256) (256,512) (512,1024) (1024,8192)
  const int nb0 = (8320 / 32) * (256 / 32);    // 2080
  const int nb1 = (256 / 32) * (512 / 32);     // 128
  const int nb2 = (512 / 32) * (1024 / 32);    // 512
  int b = blockIdx.x;
  const float* in; unsigned short* out; int K, N;
  if (b < nb0) { in = i0; out = o0; K = 8320; N = 256; }
  else if ((b -= nb0) < nb1) { in = i1; out = o1; K = 256; N = 512; }
  else if ((b -= nb1) < nb2) { in = i2; out = o2; K = 512; N = 1024; }
  else { b -= nb2; in = i3; out = o3; K = 1024; N = 8192; }
  int nx = N / 32;
  int n0 = (b % nx) * 32, k0 = (b / nx) * 32;

  __shared__ float t[32][33];
  int tx = threadIdx.x & 31, ty = threadIdx.x >> 5;  // 32x8
#pragma unroll
  for (int i = 0; i < 32; i += 8)
    t[ty + i][tx] = in[(size_t)(k0 + ty + i) * N + n0 + tx];
  __syncthreads();
#pragma unroll
  for (int i = 0; i < 32; i += 8)
    out[(size_t)(n0 + ty + i) * K + k0 + tx] = f2bf(t[tx][ty + i]);
}

// ---------------- bf16 MFMA GEMM, 128x128 tile, BK=32, swizzled LDS ----------
// ASRC: 0 = A bf16 (lda); 1 = A fp32 split (A1,K1,lda1 | A2,lda2), reg-staged cvt
//       with nontemporal loads (Adj is a 128 MB read-once stream).
// ACT:  0 = raw fp32 partial (split-K); 1 = relu -> bf16.
template <int ASRC, int ACT>
__global__ __launch_bounds__(256) void mfma_gemm(
    const unsigned short* __restrict__ Abf, int lda,
    const float* __restrict__ A1, const float* __restrict__ A2,
    int K1, int lda1, int lda2,
    const unsigned short* __restrict__ Bt, int ldb,
    const float* __restrict__ bias,
    void* __restrict__ outp, int ldo, int K, int kchunk, int pstride) {
  __shared__ unsigned short As[128 * 32];
  __shared__ unsigned short Bs[128 * 32];
  const int tid = threadIdx.x;
  const int n0 = blockIdx.x * 128, m0 = blockIdx.y * 128;
  const int wave = tid >> 6, lane = tid & 63;
  const int lq = lane >> 4, lr = lane & 15;
  const int wm = wave >> 1, wn = wave & 1;
  const int kbeg = blockIdx.z * kchunk;
  const int kend = (kbeg + kchunk < K) ? (kbeg + kchunk) : K;

  f32x4 acc[4][4] = {};

  const int G0 = tid, G1 = tid + 256;
  const int r0 = G0 >> 2, c0 = ((G0 & 3) - (r0 >> 1)) & 3;
  const int r1 = G1 >> 2, c1 = ((G1 & 3) - (r1 >> 1)) & 3;
  const int wbase0 = (tid & ~63) * 8;
  const int wbase1 = wbase0 + 256 * 8;

  for (int k0 = kbeg; k0 < kend; k0 += 32) {
    GLOAD16(Bt + (size_t)(n0 + r0) * ldb + k0 + c0 * 8, &Bs[wbase0]);
    GLOAD16(Bt + (size_t)(n0 + r1) * ldb + k0 + c1 * 8, &Bs[wbase1]);
    if (ASRC == 0) {
      GLOAD16(Abf + (size_t)(m0 + r0) * lda + k0 + c0 * 8, &As[wbase0]);
      GLOAD16(Abf + (size_t)(m0 + r1) * lda + k0 + c1 * 8, &As[wbase1]);
    } else {
#pragma unroll
      for (int q = 0; q < 2; ++q) {
        int r = q ? r1 : r0, c = q ? c1 : c0, G = q ? G1 : G0;
        int kk = k0 + c * 8;
        const float* src = (kk < K1) ? (A1 + (size_t)(m0 + r) * lda1 + kk)
                                     : (A2 + (size_t)(m0 + r) * lda2 + (kk - K1));
        f32x4 u = __builtin_nontemporal_load((const f32x4*)src);
        f32x4 vv = __builtin_nontemporal_load((const f32x4*)(src + 4));
        union { unsigned short us[8]; bf16x8 v8; } pk;
        pk.us[0] = f2bf(u[0]); pk.us[1] = f2bf(u[1]);
        pk.us[2] = f2bf(u[2]); pk.us[3] = f2bf(u[3]);
        pk.us[4] = f2bf(vv[0]); pk.us[5] = f2bf(vv[1]);
        pk.us[6] = f2bf(vv[2]); pk.us[7] = f2bf(vv[3]);
        *(bf16x8*)&As[G * 8] = pk.v8;
      }
    }
    __syncthreads();

    const int cs = (lq + (lr >> 1)) & 3;
    const int rA = wm * 64 + lr, rB = wn * 64 + lr;
    bf16x8 af[4], bfr[4];
#pragma unroll
    for (int m = 0; m < 4; ++m)
      af[m] = *(const bf16x8*)&As[(((rA + m * 16) << 2) + cs) << 3];
#pragma unroll
    for (int n = 0; n < 4; ++n)
      bfr[n] = *(const bf16x8*)&Bs[(((rB + n * 16) << 2) + cs) << 3];
#pragma unroll
    for (int m = 0; m < 4; ++m)
#pragma unroll
      for (int n = 0; n < 4; ++n)
        acc[m][n] = __builtin_amdgcn_mfma_f32_16x16x32_bf16(af[m], bfr[n], acc[m][n], 0, 0, 0);
    __syncthreads();
  }

  const int rowb = m0 + wm * 64 + lq * 4;
  const int colb = n0 + wn * 64 + lr;
  float* pout = (ACT == 0) ? ((float*)outp + (size_t)blockIdx.z * pstride) : (float*)outp;
#pragma unroll
  for (int n = 0; n < 4; ++n) {
    int c = colb + n * 16;
    float bv = (ACT == 0) ? 0.0f : bias[c];
#pragma unroll
    for (int m = 0; m < 4; ++m) {
      int r = rowb + m * 16;
#pragma unroll
      for (int j = 0; j < 4; ++j) {
        float v = acc[m][n][j] + bv;
        if (ACT == 0) {
          pout[(size_t)(r + j) * ldo + c] = v;
        } else {
          v = fmaxf(v, 0.0f);
          ((unsigned short*)outp)[(size_t)(r + j) * ldo + c] = f2bf(v);
        }
      }
    }
  }
}

// ---------------- 256x256 reg-staged double-buffer bf16 MFMA GEMM + sigmoid ----
__global__ __launch_bounds__(512, 1) void gemm256sig(
    const unsigned short* __restrict__ A, int lda,
    const unsigned short* __restrict__ Bt, int ldb,
    const float* __restrict__ bias,
    float* __restrict__ out, int ldo) {
  __shared__ unsigned short sA[2][8192];  // [buf][256 rows x 32 k] swizzled
  __shared__ unsigned short sB[2][8192];
  const int tid = threadIdx.x;
  const int wave = tid >> 6, lane = tid & 63;
  const int lq = lane >> 4, lr = lane & 15;
  const int wm = wave >> 2, wn = wave & 3;
  // bijective XCD stripe swizzle: grid 512 = 8 xcd x (16 m x 4 n)
  const int bid = blockIdx.x;
  const int xcd = bid & 7, kb = bid >> 3;
  const int n0 = (xcd * 4 + (kb & 3)) * 256;
  const int m0 = (kb >> 2) * 256;

  f32x4 acc[8][4] = {};

  const int ra0 = tid >> 2, ca0 = tid & 3;
  const int ra1 = ra0 + 128, ca1 = ca0;
  const int sl0 = (ra0 << 2) + ((ca0 + (ra0 >> 1)) & 3);
  const int sl1 = (ra1 << 2) + ((ca1 + (ra1 >> 1)) & 3);

  u16x8 gA0, gA1, gB0, gB1;
  auto g_issue = [&](int h) {
    int kk = h * 32;
    gA0 = *(const u16x8*)(A  + (size_t)(m0 + ra0) * lda + kk + ca0 * 8);
    gA1 = *(const u16x8*)(A  + (size_t)(m0 + ra1) * lda + kk + ca1 * 8);
    gB0 = *(const u16x8*)(Bt + (size_t)(n0 + ra0) * ldb + kk + ca0 * 8);
    gB1 = *(const u16x8*)(Bt + (size_t)(n0 + ra1) * ldb + kk + ca1 * 8);
  };
  auto l_write = [&](int buf) {
    *(u16x8*)&sA[buf][sl0 * 8] = gA0;
    *(u16x8*)&sA[buf][sl1 * 8] = gA1;
    *(u16x8*)&sB[buf][sl0 * 8] = gB0;
    *(u16x8*)&sB[buf][sl1 * 8] = gB1;
  };

  g_issue(0);
  l_write(0);
  g_issue(1);
  __syncthreads();

#pragma unroll 1
  for (int h = 0; h < 32; ++h) {
    const int cur = h & 1, nxt = cur ^ 1;
    const unsigned short* pa = &sA[cur][0];
    const unsigned short* pb = &sB[cur][0];
    bf16x8 afv[8], bfv[4];
#pragma unroll
    for (int n = 0; n < 4; ++n) {
      int r = wn * 64 + n * 16 + lr;
      bfv[n] = *(const bf16x8*)&pb[(size_t)(((r << 2) + ((lq + (r >> 1)) & 3)) << 3)];
    }
#pragma unroll
    for (int m = 0; m < 8; ++m) {
      int r = wm * 128 + m * 16 + lr;
      afv[m] = *(const bf16x8*)&pa[(size_t)(((r << 2) + ((lq + (r >> 1)) & 3)) << 3)];
    }
    if (h + 1 < 32) l_write(nxt);
    if (h + 2 < 32) g_issue(h + 2);
    __builtin_amdgcn_s_setprio(1);
#pragma unroll
    for (int m = 0; m < 8; ++m)
#pragma unroll
      for (int n = 0; n < 4; ++n)
        acc[m][n] = __builtin_amdgcn_mfma_f32_16x16x32_bf16(afv[m], bfv[n], acc[m][n], 0, 0, 0);
    __builtin_amdgcn_s_setprio(0);
    __syncthreads();
  }

  // ---- epilogue: sigmoid + wave-private LDS transpose -> coalesced NT stores ----
  float* lw = (wave < 4) ? ((float*)&sA[0][0] + wave * 2048)
                         : ((float*)&sB[0][0] + (wave - 4) * 2048);
  const int rowb = m0 + wm * 128;
  const int colb = n0 + wn * 64;
  float bv[4];
#pragma unroll
  for (int n = 0; n < 4; ++n) bv[n] = bias[colb + n * 16 + lr];
#pragma unroll
  for (int m = 0; m < 8; ++m) {
#pragma unroll
    for (int n = 0; n < 4; ++n)
#pragma unroll
      for (int j = 0; j < 4; ++j) {
        float v = acc[m][n][j] + bv[n];
        v = 1.0f / (1.0f + __expf(-v));
        lw[(lq * 4 + j) * 68 + n * 16 + lr] = v;
      }
    asm volatile("s_waitcnt lgkmcnt(0)" ::: "memory");  // wave-private RAW
#pragma unroll
    for (int i = 0; i < 4; ++i) {
      int chunk = i * 64 + lane;             // 0..255: 16 rows x 16 chunks
      int rr = chunk >> 4, cg = chunk & 15;
      f32x4 val = *(f32x4*)&lw[rr * 68 + cg * 4];
      __builtin_nontemporal_store(
          val, (f32x4*)(out + (size_t)(rowb + m * 16 + rr) * ldo + colb + cg * 4));
    }
    asm volatile("s_waitcnt lgkmcnt(0)" ::: "memory");  // wave-private WAR
  }
}

// ---------------- split-K partial reduce + bias + relu -> bf16 ----------------
__global__ __launch_bounds__(256) void reduceK(
    const float* __restrict__ part, const float* __restrict__ bias,
    unsigned short* __restrict__ out, int total, int N, int nsplit, int pstride) {
  int idx = blockIdx.x * 256 + threadIdx.x;
  int base = idx * 4;
  if (base >= total) return;
  float4 s = *(const float4*)(part + base);
  for (int z = 1; z < nsplit; ++z) {
    float4 p = *(const float4*)(part + (size_t)z * pstride + base);
    s.x += p.x; s.y += p.y; s.z += p.z; s.w += p.w;
  }
  float4 bv = *(const float4*)(bias + (base & (N - 1)));
  union { unsigned short us[4]; short4 v; } pk;
  pk.us[0] = f2bf(fmaxf(s.x + bv.x, 0.0f));
  pk.us[1] = f2bf(fmaxf(s.y + bv.y, 0.0f));
  pk.us[2] = f2bf(fmaxf(s.z + bv.z, 0.0f));
  pk.us[3] = f2bf(fmaxf(s.w + bv.w, 0.0f));
  *(short4*)&out[base] = pk.v;
}

// ---------------- driver ----------------
extern "C" void kernel_launch(void* const* d_in, const int* in_sizes, int n_in,
                              void* d_out, int out_size, void* d_ws, size_t ws_size,
                              hipStream_t stream) {
  const float* hM  = (const float*)d_in[0];
  const float* hD  = (const float*)d_in[1];
  const float* hT  = (const float*)d_in[2];
  const float* W1  = (const float*)d_in[3];
  const float* b1  = (const float*)d_in[4];
  const float* W2  = (const float*)d_in[5];
  const float* b2  = (const float*)d_in[6];
  const float* W3  = (const float*)d_in[7];
  const float* b3  = (const float*)d_in[8];
  const float* Adj = (const float*)d_in[9];
  const float* f1w = (const float*)d_in[10];
  const float* f1b = (const float*)d_in[11];
  const float* f2w = (const float*)d_in[12];
  const float* f2b = (const float*)d_in[13];
  const float* f3w = (const float*)d_in[14];
  const float* f3b = (const float*)d_in[15];
  const float* f4w = (const float*)d_in[16];
  const float* f4b = (const float*)d_in[17];
  const int* edges = (const int*)d_in[18];
  const int* leftIndex = (const int*)d_in[20];
  const int E = in_sizes[18] / 12;  // 500000
  (void)ws_size; (void)n_in; (void)out_size;

  char* w = (char*)d_ws;
  size_t off = 0;
  auto alloc = [&](size_t bytes) {
    void* p = w + off;
    off = (off + bytes + 255) & ~(size_t)255;
    return p;
  };
  int*   row_start = (int*)  alloc((size_t)NTYPE * (NN + 1) * 4);
  float* inv_out   = (float*)alloc((size_t)NTYPE * NN * 4);
  float* inv_in    = (float*)alloc((size_t)NTYPE * NN * 4);
  float* featA     = (float*)alloc((size_t)3 * NN * 128 * 4);   // persists to l1norm
  size_t ubase = off;  // ---- union region: GNN view ----
  int*            csr   = (int*)           alloc((size_t)NTYPE * E * 4);        // 12 MB
  unsigned short* xs6   = (unsigned short*)alloc((size_t)NTYPE * NN * 128 * 2); // 12.6 MB
  float*          featB = (float*)         alloc((size_t)3 * NN * 128 * 4);     // 12.6 MB
  int* deg_part = (int*)csr;            // aliases csr (dead until scatter)
  int* soff     = (int*)featB;          // aliases featB (dead until L=1)
  // ---- union region: MLP view (same bytes, GNN buffers dead) ----
  size_t moff = ubase;
  auto malloc2 = [&](size_t bytes) {
    void* p = w + moff;
    moff = (moff + bytes + 255) & ~(size_t)255;
    return p;
  };
  unsigned short* w1t = (unsigned short*)malloc2((size_t)256 * 8320 * 2);
  unsigned short* w2t = (unsigned short*)malloc2((size_t)512 * 256 * 2);
  unsigned short* w3t = (unsigned short*)malloc2((size_t)1024 * 512 * 2);
  unsigned short* w4t = (unsigned short*)malloc2((size_t)8192 * 1024 * 2);
  unsigned short* x1b = (unsigned short*)malloc2((size_t)4096 * 256 * 2);
  unsigned short* x2b = (unsigned short*)malloc2((size_t)4096 * 512 * 2);
  unsigned short* x3b = (unsigned short*)malloc2((size_t)4096 * 1024 * 2);
  float*          x1p = (float*)malloc2((size_t)8 * 4096 * 256 * 4);  // split-K x8 partials

  // ---- CSR build (no global atomics anywhere) ----
  hist_degree<<<dim3(BPT, NTYPE, 2), 256, 0, stream>>>(edges, deg_part, E);
  build_offsets<<<NTYPE, 1024, 0, stream>>>(deg_part, inv_out, inv_in, row_start, soff);
  scatter_v2<<<dim3(8, BPT), 256, 0, stream>>>(edges, soff, csr, E);

  // ---- 3 GNN layers, dead-branch pruned ----
  // Only hM3[leftIndex : leftIndex+4096] is consumed downstream.
  const size_t comp = (size_t)NN * 128;
  gemm64xs<<<dim3(1, NN / 64, 6), 256, 0, stream>>>(
      hM, hD, hT, 256, W1, inv_out, xs6, 256, 64, 0x543210);
  aggregate3<64><<<dim3(NN / 4, 3), 256, 0, stream>>>(
      xs6, csr, row_start, inv_in, b1, featA, E, 0x020100, nullptr);
  gemm64xs<<<dim3(1, NN / 64, 4), 256, 0, stream>>>(
      featA, featA + comp, featA + 2 * comp, 64, W2, inv_out, xs6, 64, 64, 0x5420);
  aggregate3<64><<<dim3(NN / 4, 2), 256, 0, stream>>>(
      xs6, csr, row_start, inv_in, b2, featB, E, 0x0201, nullptr);
  gemm64xs<<<dim3(2, NN / 64, 2), 256, 0, stream>>>(
      featB, featB + comp, featB + 2 * comp, 64, W3, inv_out, xs6, 64, 128, 0x31);
  aggregate3<128><<<dim3(4096 / 4, 1), 256, 0, stream>>>(
      xs6, csr, row_start, inv_in, b3, featA, E, 0x00, leftIndex);

  float* fake = (float*)d_out;                        // 4096 x 128 fp32
  float* outx = (float*)d_out + (size_t)4096 * 128;   // 4096 x 8192 fp32
  l1norm_fake<<<4096 / 4, 256, 0, stream>>>(featA, leftIndex, fake);

  // ---- weight cast+transpose, fused (after GNN: union region now safe) ----
  const int ncast = (8320 / 32) * (256 / 32) + (256 / 32) * (512 / 32) +
                    (512 / 32) * (1024 / 32) + (8192 / 32) * (1024 / 32);
  castT4<<<ncast, 256, 0, stream>>>(f1w, w1t, f2w, w2t, f3w, w3t, f4w, w4t);

  // ---- MLP (bf16 MFMA) ----
  mfma_gemm<1, 0><<<dim3(256 / 128, 4096 / 128, 8), 256, 0, stream>>>(
      nullptr, 0, Adj, fake, 8192, 8192, 128, w1t, 8320, nullptr,
      x1p, 256, 8320, 1056, 4096 * 256);
  reduceK<<<(4096 * 256 / 4 + 255) / 256, 256, 0, stream>>>(
      x1p, f1b, x1b, 4096 * 256, 256, 8, 4096 * 256);
  mfma_gemm<0, 1><<<dim3(512 / 128, 4096 / 128), 256, 0, stream>>>(
      x1b, 256, nullptr, nullptr, 0, 0, 0, w2t, 256, f2b, x2b, 512, 256, 256, 0);
  mfma_gemm<0, 1><<<dim3(1024 / 128, 4096 / 128), 256, 0, stream>>>(
      x2b, 512, nullptr, nullptr, 0, 0, 0, w3t, 512, f3b, x3b, 1024, 512, 512, 0);
  gemm256sig<<<512, 512, 0, stream>>>(x3b, 1024, w4t, 1024, f4b, outx, 8192);
}

// Round 15
// 442.240 us; speedup vs baseline: 1.2962x; 1.2962x over previous
//
#include <hip/hip_runtime.h>
#include <hip/hip_bf16.h>
#include <cstdint>
#include <cstddef>
#include <type_traits>

#define NN 8192
#define NTYPE 6
#define BPT 32  // histogram/scatter slices per (type, role)

typedef __attribute__((ext_vector_type(8))) short bf16x8;
typedef __attribute__((ext_vector_type(4))) float f32x4;
typedef __attribute__((ext_vector_type(4))) unsigned short u16x4;
typedef __attribute__((ext_vector_type(8))) unsigned short u16x8;

#define GLOAD16(g, l)                                                        \
  __builtin_amdgcn_global_load_lds(                                          \
      (const __attribute__((address_space(1))) void*)(g),                    \
      (__attribute__((address_space(3))) void*)(l), 16, 0, 0)

static __device__ __forceinline__ unsigned short f2bf(float f) {
  union { float f; unsigned u; } x; x.f = f;
  unsigned u = x.u + 0x7fffu + ((x.u >> 16) & 1u);
  return (unsigned short)(u >> 16);
}
static __device__ __forceinline__ float bf2f(unsigned short u) {
  union { unsigned u32; float f; } x; x.u32 = (unsigned)u << 16; return x.f;
}

// ---------------- degree histograms: LDS-privatized, non-atomic flush ----------------
__global__ __launch_bounds__(256) void hist_degree(
    const int* __restrict__ edges, int* __restrict__ partial, int E) {
  const int b = blockIdx.x, t = blockIdx.y, role = blockIdx.z;
  __shared__ int h[NN];
  for (int i = threadIdx.x; i < NN; i += 256) h[i] = 0;
  __syncthreads();
  const int* ids = edges + ((size_t)t * 2 + role) * E;
  int ch = (E + BPT - 1) / BPT;
  int beg = b * ch, end = (beg + ch < E) ? beg + ch : E;
  for (int i = beg + threadIdx.x; i < end; i += 256)
    atomicAdd(&h[__builtin_nontemporal_load(ids + i)], 1);
  __syncthreads();
  int* dst = partial + ((size_t)((role * NTYPE + t) * BPT + b)) * NN;
  for (int i = threadIdx.x; i < NN; i += 256) dst[i] = h[i];
}

// sum partials -> inv_out, inv_in, incnt (for scan)
__global__ __launch_bounds__(256) void reduce_deg(
    const int* __restrict__ partial, float* __restrict__ inv_out,
    float* __restrict__ inv_in, int* __restrict__ incnt) {
  int i = blockIdx.x * 256 + threadIdx.x;
  if (i >= NTYPE * NN) return;
  int t = i >> 13, n = i & (NN - 1);
  const int* ps = partial + ((size_t)(t * BPT)) * NN + n;
  const int* pd = partial + ((size_t)((NTYPE + t) * BPT)) * NN + n;
  int so = 0, sd = 0;
#pragma unroll 8
  for (int b = 0; b < BPT; ++b) { so += ps[(size_t)b * NN]; sd += pd[(size_t)b * NN]; }
  inv_out[i] = rsqrtf(fmaxf((float)so, 1.0f));
  inv_in[i]  = rsqrtf(fmaxf((float)sd, 1.0f));
  incnt[i]   = sd;
}

// one block per edge type: exclusive scan of indeg -> row_start
__global__ void scan_rows(const int* __restrict__ incnt, int* __restrict__ row_start) {
  int t = blockIdx.x;
  int i = threadIdx.x;
  const int* c = incnt + t * NN;
  int v[8], s = 0;
#pragma unroll
  for (int j = 0; j < 8; ++j) { v[j] = c[i * 8 + j]; s += v[j]; }
  __shared__ int p[1024];
  p[i] = s;
  __syncthreads();
  for (int d = 1; d < 1024; d <<= 1) {
    int x = (i >= d) ? p[i - d] : 0;
    __syncthreads();
    p[i] += x;
    __syncthreads();
  }
  int run = p[i] - s;
  int* rs = row_start + t * (NN + 1);
#pragma unroll
  for (int j = 0; j < 8; ++j) { rs[i * 8 + j] = run; run += v[j]; }
  if (i == 1023) rs[NN] = run;
}

// soff[t][s][d] = row_start[t][d] + sum_{s'<s} indeg_part[t][s'][d]
__global__ __launch_bounds__(256) void slice_offsets(
    const int* __restrict__ partial, const int* __restrict__ row_start,
    int* __restrict__ soff) {
  int i = blockIdx.x * 256 + threadIdx.x;
  if (i >= NTYPE * NN) return;
  int t = i >> 13, d = i & (NN - 1);
  const int* pd = partial + ((size_t)((NTYPE + t) * BPT)) * NN + d;
  int run = row_start[t * (NN + 1) + d];
  int* o = soff + ((size_t)t * BPT) * NN + d;
#pragma unroll 8
  for (int s = 0; s < BPT; ++s) { o[(size_t)s * NN] = run; run += pd[(size_t)s * NN]; }
}

// atomic-free scatter: LDS cursors seeded from soff; grid (8, BPT), x = type
__global__ __launch_bounds__(256) void scatter_v2(
    const int* __restrict__ edges, const int* __restrict__ soff,
    int* __restrict__ csr, int E) {
  int t = blockIdx.x;
  if (t >= NTYPE) return;
  int s = blockIdx.y;
  __shared__ int cur[NN];
  const int* o = soff + ((size_t)(t * BPT + s)) * NN;
  for (int i = threadIdx.x; i < NN; i += 256) cur[i] = o[i];
  __syncthreads();
  int ch = (E + BPT - 1) / BPT;
  int beg = s * ch, end = (beg + ch < E) ? beg + ch : E;
  const int* eb = edges + (size_t)t * 2 * E;
  int* out = csr + (size_t)t * E;
  for (int i = beg + threadIdx.x; i < end; i += 256) {
    int src = __builtin_nontemporal_load(eb + i);
    int dst = __builtin_nontemporal_load(eb + E + i);
    int pos = atomicAdd(&cur[dst], 1);
    out[pos] = src;
  }
}

// ---------------- batched 64x64 fp32 GEMM for GNN xs, bf16 out ----------------
// tpack: 4-bit packed list of active edge types, indexed by blockIdx.z.
__global__ __launch_bounds__(256) void gemm64xs(
    const float* __restrict__ p0, const float* __restrict__ p1,
    const float* __restrict__ p2, int lda,
    const float* __restrict__ WL, const float* __restrict__ inv_out,
    unsigned short* __restrict__ xs6, int F, int H, int tpack) {
  const int t = (tpack >> (4 * blockIdx.z)) & 15;
  const int srcc[6] = {0, 1, 0, 2, 2, 1};
  const float* A = (srcc[t] == 0) ? p0 : (srcc[t] == 1) ? p1 : p2;
  const float* B = WL + (size_t)t * F * H;  // (F,H) row-major, ldb=H
  const float* rscale = inv_out + t * NN;
  unsigned short* out = xs6 + (size_t)t * NN * H;

  __shared__ float As[16][68];
  __shared__ float Bs[16][68];
  int tid = threadIdx.x;
  int n0 = blockIdx.x * 64, m0 = blockIdx.y * 64;
  int ar = tid >> 2, ac = (tid & 3) * 4;
  int br = tid >> 4, bc = (tid & 15) * 4;
  int tx = tid & 15, ty = tid >> 4;
  float acc[4][4] = {};
  for (int k0 = 0; k0 < F; k0 += 16) {
    float4 av = *(const float4*)(A + (size_t)(m0 + ar) * lda + k0 + ac);
    As[ac + 0][ar] = av.x; As[ac + 1][ar] = av.y;
    As[ac + 2][ar] = av.z; As[ac + 3][ar] = av.w;
    *(float4*)&Bs[br][bc] = *(const float4*)(B + (size_t)(k0 + br) * H + n0 + bc);
    __syncthreads();
#pragma unroll
    for (int kk = 0; kk < 16; ++kk) {
      float4 a = *(const float4*)&As[kk][ty * 4];
      float4 b = *(const float4*)&Bs[kk][tx * 4];
      float aa[4] = {a.x, a.y, a.z, a.w};
      float bb[4] = {b.x, b.y, b.z, b.w};
#pragma unroll
      for (int i = 0; i < 4; ++i)
#pragma unroll
        for (int j = 0; j < 4; ++j) acc[i][j] += aa[i] * bb[j];
    }
    __syncthreads();
  }
#pragma unroll
  for (int i = 0; i < 4; ++i) {
    int r = m0 + ty * 4 + i;
    float sc = rscale[r];
    union { unsigned short us[4]; short4 v; } pk;
#pragma unroll
    for (int j = 0; j < 4; ++j) pk.us[j] = f2bf(acc[i][j] * sc);
    *(short4*)&out[(size_t)r * H + n0 + tx * 4] = pk.v;
  }
}

// ---------------- CSR aggregation v3: 4 edges/VMEM-instr vectorized gather ----
// cpack: 8-bit packed list of active target classes, indexed by blockIdx.y.
// dbase: optional device scalar added to the target-row index (dependency-cone
// prune: the final layer only needs rows [leftIndex, leftIndex+4096)).
template <int H>
__global__ __launch_bounds__(256) void aggregate3(
    const unsigned short* __restrict__ xs6, const int* __restrict__ csr,
    const int* __restrict__ row_start, const float* __restrict__ inv_in,
    const float* __restrict__ bL, float* __restrict__ feat_out, int E, int cpack,
    const int* __restrict__ dbase) {
  constexpr int VE = H / 16;
  const int c = (cpack >> (8 * blockIdx.y)) & 0xff;
  const int taT[3] = {1, 0, 2}, tbT[3] = {3, 4, 5};
  int wave = threadIdx.x >> 6, lane = threadIdx.x & 63;
  int slot = lane >> 4, colg = lane & 15;
  int d = blockIdx.x * 4 + wave;
  if (dbase) d += dbase[0];

  float out[VE];
#pragma unroll
  for (int v = 0; v < VE; ++v) out[v] = 0.f;

#pragma unroll
  for (int half = 0; half < 2; ++half) {
    int t = half ? tbT[c] : taT[c];
    const unsigned short* xs = xs6 + (size_t)t * NN * H;
    const int* cs = csr + (size_t)t * E;
    const int* rs = row_start + t * (NN + 1);
    int b = rs[d], e = rs[d + 1];
    float a[VE];
#pragma unroll
    for (int v = 0; v < VE; ++v) a[v] = 0.f;
    for (int j0 = b; j0 < e; j0 += 64) {
      int myj = j0 + lane;
      int idxv = (myj < e) ? cs[myj] : 0;
      int cnt = e - j0; if (cnt > 64) cnt = 64;
      int g = 0;
      for (; (g + 1) * 4 <= cnt; ++g) {
        int is = __shfl(idxv, g * 4 + slot);
        const unsigned short* xr = xs + (size_t)is * H + colg * VE;
        if constexpr (VE == 4) {
          u16x4 x = *(const u16x4*)xr;
#pragma unroll
          for (int v = 0; v < 4; ++v) a[v] += bf2f(x[v]);
        } else {
          u16x8 x = *(const u16x8*)xr;
#pragma unroll
          for (int v = 0; v < 8; ++v) a[v] += bf2f(x[v]);
        }
      }
      int done = g * 4;
      if (done < cnt) {
        int gi = done + slot;
        int is = __shfl(idxv, gi < cnt ? gi : 0);
        float wt = (gi < cnt) ? 1.0f : 0.0f;
        const unsigned short* xr = xs + (size_t)is * H + colg * VE;
        if constexpr (VE == 4) {
          u16x4 x = *(const u16x4*)xr;
#pragma unroll
          for (int v = 0; v < 4; ++v) a[v] += wt * bf2f(x[v]);
        } else {
          u16x8 x = *(const u16x8*)xr;
#pragma unroll
          for (int v = 0; v < 8; ++v) a[v] += wt * bf2f(x[v]);
        }
      }
    }
    float sc = inv_in[t * NN + d];
#pragma unroll
    for (int v = 0; v < VE; ++v) out[v] += a[v] * sc;
  }
#pragma unroll
  for (int v = 0; v < VE; ++v) {
    out[v] += __shfl_xor(out[v], 16);
    out[v] += __shfl_xor(out[v], 32);
  }
  if (lane < 16) {
    int ta = taT[c], tb = tbT[c];
    float* o = feat_out + (size_t)c * NN * 128 + (size_t)d * H + colg * VE;
    const float* ba = bL + ta * H + colg * VE;
    const float* bb = bL + tb * H + colg * VE;
    float4 w0 = make_float4(out[0] + ba[0] + bb[0], out[1] + ba[1] + bb[1],
                            out[2] + ba[2] + bb[2], out[3] + ba[3] + bb[3]);
    *(float4*)o = w0;
    if constexpr (VE == 8) {
      float4 w1 = make_float4(out[4] + ba[4] + bb[4], out[5] + ba[5] + bb[5],
                              out[6] + ba[6] + bb[6], out[7] + ba[7] + bb[7]);
      *(float4*)(o + 4) = w1;
    }
  }
}

// ---------------- row L1-normalize hM3 -> fake (fp32, to d_out) ----------------
__global__ __launch_bounds__(256) void l1norm_fake(
    const float* __restrict__ hM3, const int* __restrict__ leftIndex,
    float* __restrict__ fake) {
  int wave = threadIdx.x >> 6, lane = threadIdx.x & 63;
  int r = blockIdx.x * 4 + wave;
  int row = leftIndex[0] + r;
  const float* x = hM3 + (size_t)row * 128;
  float a = x[lane], b = x[64 + lane];
  float s = fabsf(a) + fabsf(b);
#pragma unroll
  for (int d = 1; d < 64; d <<= 1) s += __shfl_xor(s, d);
  float inv = 1.0f / fmaxf(s, 1e-12f);
  fake[(size_t)r * 128 + lane]      = a * inv;
  fake[(size_t)r * 128 + 64 + lane] = b * inv;
}

// ---------------- fused cast + transpose fp32 (K,N) -> bf16 (N,K), 4 weights ----
__global__ __launch_bounds__(256) void castT4(
    const float* __restrict__ i0, unsigned short* __restrict__ o0,
    const float* __restrict__ i1, unsigned short* __restrict__ o1,
    const float* __restrict__ i2, unsigned short* __restrict__ o2,
    const float* __restrict__ i3, unsigned short* __restrict__ o3) {
  // segments (K, N): (8320,256) (256,512) (512,1024) (1024,8192)
  const int nb0 = (8320 / 32) * (256 / 32);    // 2080
  const int nb1 = (256 / 32) * (512 / 32);     // 128
  const int nb2 = (512 / 32) * (1024 / 32);    // 512
  int b = blockIdx.x;
  const float* in; unsigned short* out; int K, N;
  if (b < nb0) { in = i0; out = o0; K = 8320; N = 256; }
  else if ((b -= nb0) < nb1) { in = i1; out = o1; K = 256; N = 512; }
  else if ((b -= nb1) < nb2) { in = i2; out = o2; K = 512; N = 1024; }
  else { b -= nb2; in = i3; out = o3; K = 1024; N = 8192; }
  int nx = N / 32;
  int n0 = (b % nx) * 32, k0 = (b / nx) * 32;

  __shared__ float t[32][33];
  int tx = threadIdx.x & 31, ty = threadIdx.x >> 5;  // 32x8
#pragma unroll
  for (int i = 0; i < 32; i += 8)
    t[ty + i][tx] = in[(size_t)(k0 + ty + i) * N + n0 + tx];
  __syncthreads();
#pragma unroll
  for (int i = 0; i < 32; i += 8)
    out[(size_t)(n0 + ty + i) * K + k0 + tx] = f2bf(t[tx][ty + i]);
}

// ---------------- bf16 MFMA GEMM, 128x128 tile, BK=32, swizzled LDS ----------
// ASRC: 0 = A bf16 (lda); 1 = A fp32 split (A1,K1,lda1 | A2,lda2), reg-staged cvt
//       with nontemporal loads (Adj is a 128 MB read-once stream).
// ACT:  0 = raw fp32 partial (split-K); 1 = relu -> bf16.
template <int ASRC, int ACT>
__global__ __launch_bounds__(256) void mfma_gemm(
    const unsigned short* __restrict__ Abf, int lda,
    const float* __restrict__ A1, const float* __restrict__ A2,
    int K1, int lda1, int lda2,
    const unsigned short* __restrict__ Bt, int ldb,
    const float* __restrict__ bias,
    void* __restrict__ outp, int ldo, int K, int kchunk, int pstride) {
  __shared__ unsigned short As[128 * 32];
  __shared__ unsigned short Bs[128 * 32];
  const int tid = threadIdx.x;
  const int n0 = blockIdx.x * 128, m0 = blockIdx.y * 128;
  const int wave = tid >> 6, lane = tid & 63;
  const int lq = lane >> 4, lr = lane & 15;
  const int wm = wave >> 1, wn = wave & 1;
  const int kbeg = blockIdx.z * kchunk;
  const int kend = (kbeg + kchunk < K) ? (kbeg + kchunk) : K;

  f32x4 acc[4][4] = {};

  const int G0 = tid, G1 = tid + 256;
  const int r0 = G0 >> 2, c0 = ((G0 & 3) - (r0 >> 1)) & 3;
  const int r1 = G1 >> 2, c1 = ((G1 & 3) - (r1 >> 1)) & 3;
  const int wbase0 = (tid & ~63) * 8;
  const int wbase1 = wbase0 + 256 * 8;

  for (int k0 = kbeg; k0 < kend; k0 += 32) {
    GLOAD16(Bt + (size_t)(n0 + r0) * ldb + k0 + c0 * 8, &Bs[wbase0]);
    GLOAD16(Bt + (size_t)(n0 + r1) * ldb + k0 + c1 * 8, &Bs[wbase1]);
    if (ASRC == 0) {
      GLOAD16(Abf + (size_t)(m0 + r0) * lda + k0 + c0 * 8, &As[wbase0]);
      GLOAD16(Abf + (size_t)(m0 + r1) * lda + k0 + c1 * 8, &As[wbase1]);
    } else {
#pragma unroll
      for (int q = 0; q < 2; ++q) {
        int r = q ? r1 : r0, c = q ? c1 : c0, G = q ? G1 : G0;
        int kk = k0 + c * 8;
        const float* src = (kk < K1) ? (A1 + (size_t)(m0 + r) * lda1 + kk)
                                     : (A2 + (size_t)(m0 + r) * lda2 + (kk - K1));
        f32x4 u = __builtin_nontemporal_load((const f32x4*)src);
        f32x4 vv = __builtin_nontemporal_load((const f32x4*)(src + 4));
        union { unsigned short us[8]; bf16x8 v8; } pk;
        pk.us[0] = f2bf(u[0]); pk.us[1] = f2bf(u[1]);
        pk.us[2] = f2bf(u[2]); pk.us[3] = f2bf(u[3]);
        pk.us[4] = f2bf(vv[0]); pk.us[5] = f2bf(vv[1]);
        pk.us[6] = f2bf(vv[2]); pk.us[7] = f2bf(vv[3]);
        *(bf16x8*)&As[G * 8] = pk.v8;
      }
    }
    __syncthreads();

    const int cs = (lq + (lr >> 1)) & 3;
    const int rA = wm * 64 + lr, rB = wn * 64 + lr;
    bf16x8 af[4], bfr[4];
#pragma unroll
    for (int m = 0; m < 4; ++m)
      af[m] = *(const bf16x8*)&As[(((rA + m * 16) << 2) + cs) << 3];
#pragma unroll
    for (int n = 0; n < 4; ++n)
      bfr[n] = *(const bf16x8*)&Bs[(((rB + n * 16) << 2) + cs) << 3];
#pragma unroll
    for (int m = 0; m < 4; ++m)
#pragma unroll
      for (int n = 0; n < 4; ++n)
        acc[m][n] = __builtin_amdgcn_mfma_f32_16x16x32_bf16(af[m], bfr[n], acc[m][n], 0, 0, 0);
    __syncthreads();
  }

  const int rowb = m0 + wm * 64 + lq * 4;
  const int colb = n0 + wn * 64 + lr;
  float* pout = (ACT == 0) ? ((float*)outp + (size_t)blockIdx.z * pstride) : (float*)outp;
#pragma unroll
  for (int n = 0; n < 4; ++n) {
    int c = colb + n * 16;
    float bv = (ACT == 0) ? 0.0f : bias[c];
#pragma unroll
    for (int m = 0; m < 4; ++m) {
      int r = rowb + m * 16;
#pragma unroll
      for (int j = 0; j < 4; ++j) {
        float v = acc[m][n][j] + bv;
        if (ACT == 0) {
          pout[(size_t)(r + j) * ldo + c] = v;
        } else {
          v = fmaxf(v, 0.0f);
          ((unsigned short*)outp)[(size_t)(r + j) * ldo + c] = f2bf(v);
        }
      }
    }
  }
}

// ---------------- 256x256 reg-staged double-buffer bf16 MFMA GEMM + sigmoid ----
__global__ __launch_bounds__(512, 1) void gemm256sig(
    const unsigned short* __restrict__ A, int lda,
    const unsigned short* __restrict__ Bt, int ldb,
    const float* __restrict__ bias,
    float* __restrict__ out, int ldo) {
  __shared__ unsigned short sA[2][8192];  // [buf][256 rows x 32 k] swizzled
  __shared__ unsigned short sB[2][8192];
  const int tid = threadIdx.x;
  const int wave = tid >> 6, lane = tid & 63;
  const int lq = lane >> 4, lr = lane & 15;
  const int wm = wave >> 2, wn = wave & 3;
  // bijective XCD stripe swizzle: grid 512 = 8 xcd x (16 m x 4 n)
  const int bid = blockIdx.x;
  const int xcd = bid & 7, kb = bid >> 3;
  const int n0 = (xcd * 4 + (kb & 3)) * 256;
  const int m0 = (kb >> 2) * 256;

  f32x4 acc[8][4] = {};

  const int ra0 = tid >> 2, ca0 = tid & 3;
  const int ra1 = ra0 + 128, ca1 = ca0;
  const int sl0 = (ra0 << 2) + ((ca0 + (ra0 >> 1)) & 3);
  const int sl1 = (ra1 << 2) + ((ca1 + (ra1 >> 1)) & 3);

  u16x8 gA0, gA1, gB0, gB1;
  auto g_issue = [&](int h) {
    int kk = h * 32;
    gA0 = *(const u16x8*)(A  + (size_t)(m0 + ra0) * lda + kk + ca0 * 8);
    gA1 = *(const u16x8*)(A  + (size_t)(m0 + ra1) * lda + kk + ca1 * 8);
    gB0 = *(const u16x8*)(Bt + (size_t)(n0 + ra0) * ldb + kk + ca0 * 8);
    gB1 = *(const u16x8*)(Bt + (size_t)(n0 + ra1) * ldb + kk + ca1 * 8);
  };
  auto l_write = [&](int buf) {
    *(u16x8*)&sA[buf][sl0 * 8] = gA0;
    *(u16x8*)&sA[buf][sl1 * 8] = gA1;
    *(u16x8*)&sB[buf][sl0 * 8] = gB0;
    *(u16x8*)&sB[buf][sl1 * 8] = gB1;
  };

  g_issue(0);
  l_write(0);
  g_issue(1);
  __syncthreads();

#pragma unroll 1
  for (int h = 0; h < 32; ++h) {
    const int cur = h & 1, nxt = cur ^ 1;
    const unsigned short* pa = &sA[cur][0];
    const unsigned short* pb = &sB[cur][0];
    bf16x8 afv[8], bfv[4];
#pragma unroll
    for (int n = 0; n < 4; ++n) {
      int r = wn * 64 + n * 16 + lr;
      bfv[n] = *(const bf16x8*)&pb[(size_t)(((r << 2) + ((lq + (r >> 1)) & 3)) << 3)];
    }
#pragma unroll
    for (int m = 0; m < 8; ++m) {
      int r = wm * 128 + m * 16 + lr;
      afv[m] = *(const bf16x8*)&pa[(size_t)(((r << 2) + ((lq + (r >> 1)) & 3)) << 3)];
    }
    if (h + 1 < 32) l_write(nxt);
    if (h + 2 < 32) g_issue(h + 2);
    __builtin_amdgcn_s_setprio(1);
#pragma unroll
    for (int m = 0; m < 8; ++m)
#pragma unroll
      for (int n = 0; n < 4; ++n)
        acc[m][n] = __builtin_amdgcn_mfma_f32_16x16x32_bf16(afv[m], bfv[n], acc[m][n], 0, 0, 0);
    __builtin_amdgcn_s_setprio(0);
    __syncthreads();
  }

  // ---- epilogue: sigmoid + wave-private LDS transpose -> coalesced NT stores ----
  float* lw = (wave < 4) ? ((float*)&sA[0][0] + wave * 2048)
                         : ((float*)&sB[0][0] + (wave - 4) * 2048);
  const int rowb = m0 + wm * 128;
  const int colb = n0 + wn * 64;
  float bv[4];
#pragma unroll
  for (int n = 0; n < 4; ++n) bv[n] = bias[colb + n * 16 + lr];
#pragma unroll
  for (int m = 0; m < 8; ++m) {
#pragma unroll
    for (int n = 0; n < 4; ++n)
#pragma unroll
      for (int j = 0; j < 4; ++j) {
        float v = acc[m][n][j] + bv[n];
        v = 1.0f / (1.0f + __expf(-v));
        lw[(lq * 4 + j) * 68 + n * 16 + lr] = v;
      }
    asm volatile("s_waitcnt lgkmcnt(0)" ::: "memory");  // wave-private RAW
#pragma unroll
    for (int i = 0; i < 4; ++i) {
      int chunk = i * 64 + lane;             // 0..255: 16 rows x 16 chunks
      int rr = chunk >> 4, cg = chunk & 15;
      f32x4 val = *(f32x4*)&lw[rr * 68 + cg * 4];
      __builtin_nontemporal_store(
          val, (f32x4*)(out + (size_t)(rowb + m * 16 + rr) * ldo + colb + cg * 4));
    }
    asm volatile("s_waitcnt lgkmcnt(0)" ::: "memory");  // wave-private WAR
  }
}

// ---------------- split-K partial reduce + bias + relu -> bf16 ----------------
__global__ __launch_bounds__(256) void reduceK(
    const float* __restrict__ part, const float* __restrict__ bias,
    unsigned short* __restrict__ out, int total, int N, int nsplit, int pstride) {
  int idx = blockIdx.x * 256 + threadIdx.x;
  int base = idx * 4;
  if (base >= total) return;
  float4 s = *(const float4*)(part + base);
  for (int z = 1; z < nsplit; ++z) {
    float4 p = *(const float4*)(part + (size_t)z * pstride + base);
    s.x += p.x; s.y += p.y; s.z += p.z; s.w += p.w;
  }
  float4 bv = *(const float4*)(bias + (base & (N - 1)));
  union { unsigned short us[4]; short4 v; } pk;
  pk.us[0] = f2bf(fmaxf(s.x + bv.x, 0.0f));
  pk.us[1] = f2bf(fmaxf(s.y + bv.y, 0.0f));
  pk.us[2] = f2bf(fmaxf(s.z + bv.z, 0.0f));
  pk.us[3] = f2bf(fmaxf(s.w + bv.w, 0.0f));
  *(short4*)&out[base] = pk.v;
}

// ---------------- driver ----------------
extern "C" void kernel_launch(void* const* d_in, const int* in_sizes, int n_in,
                              void* d_out, int out_size, void* d_ws, size_t ws_size,
                              hipStream_t stream) {
  const float* hM  = (const float*)d_in[0];
  const float* hD  = (const float*)d_in[1];
  const float* hT  = (const float*)d_in[2];
  const float* W1  = (const float*)d_in[3];
  const float* b1  = (const float*)d_in[4];
  const float* W2  = (const float*)d_in[5];
  const float* b2  = (const float*)d_in[6];
  const float* W3  = (const float*)d_in[7];
  const float* b3  = (const float*)d_in[8];
  const float* Adj = (const float*)d_in[9];
  const float* f1w = (const float*)d_in[10];
  const float* f1b = (const float*)d_in[11];
  const float* f2w = (const float*)d_in[12];
  const float* f2b = (const float*)d_in[13];
  const float* f3w = (const float*)d_in[14];
  const float* f3b = (const float*)d_in[15];
  const float* f4w = (const float*)d_in[16];
  const float* f4b = (const float*)d_in[17];
  const int* edges = (const int*)d_in[18];
  const int* leftIndex = (const int*)d_in[20];
  const int E = in_sizes[18] / 12;  // 500000
  (void)ws_size; (void)n_in; (void)out_size;

  char* w = (char*)d_ws;
  size_t off = 0;
  auto alloc = [&](size_t bytes) {
    void* p = w + off;
    off = (off + bytes + 255) & ~(size_t)255;
    return p;
  };
  int*   row_start = (int*)  alloc((size_t)NTYPE * (NN + 1) * 4);
  int*   incnt     = (int*)  alloc((size_t)NTYPE * NN * 4);
  float* inv_out   = (float*)alloc((size_t)NTYPE * NN * 4);
  float* inv_in    = (float*)alloc((size_t)NTYPE * NN * 4);
  float* featA     = (float*)alloc((size_t)3 * NN * 128 * 4);   // persists to l1norm
  size_t ubase = off;  // ---- union region: GNN view ----
  int*            csr   = (int*)           alloc((size_t)NTYPE * E * 4);        // 12 MB
  unsigned short* xs6   = (unsigned short*)alloc((size_t)NTYPE * NN * 128 * 2); // 12.6 MB
  float*          featB = (float*)         alloc((size_t)3 * NN * 128 * 4);     // 12.6 MB
  int* deg_part = (int*)csr;            // aliases csr (dead until scatter)
  int* soff     = (int*)featB;          // aliases featB (dead until L=1)
  // ---- union region: MLP view (same bytes, GNN buffers dead) ----
  size_t moff = ubase;
  auto malloc2 = [&](size_t bytes) {
    void* p = w + moff;
    moff = (moff + bytes + 255) & ~(size_t)255;
    return p;
  };
  unsigned short* w1t = (unsigned short*)malloc2((size_t)256 * 8320 * 2);
  unsigned short* w2t = (unsigned short*)malloc2((size_t)512 * 256 * 2);
  unsigned short* w3t = (unsigned short*)malloc2((size_t)1024 * 512 * 2);
  unsigned short* w4t = (unsigned short*)malloc2((size_t)8192 * 1024 * 2);
  unsigned short* x1b = (unsigned short*)malloc2((size_t)4096 * 256 * 2);
  unsigned short* x2b = (unsigned short*)malloc2((size_t)4096 * 512 * 2);
  unsigned short* x3b = (unsigned short*)malloc2((size_t)4096 * 1024 * 2);
  float*          x1p = (float*)malloc2((size_t)8 * 4096 * 256 * 4);  // split-K x8 partials

  // ---- CSR build (no global atomics anywhere) ----
  hist_degree<<<dim3(BPT, NTYPE, 2), 256, 0, stream>>>(edges, deg_part, E);
  reduce_deg<<<(NTYPE * NN + 255) / 256, 256, 0, stream>>>(deg_part, inv_out, inv_in, incnt);
  scan_rows<<<NTYPE, 1024, 0, stream>>>(incnt, row_start);
  slice_offsets<<<(NTYPE * NN + 255) / 256, 256, 0, stream>>>(deg_part, row_start, soff);
  scatter_v2<<<dim3(8, BPT), 256, 0, stream>>>(edges, soff, csr, E);

  // ---- 3 GNN layers, dead-branch pruned ----
  // Only hM3[leftIndex : leftIndex+4096] is consumed downstream.
  const size_t comp = (size_t)NN * 128;
  gemm64xs<<<dim3(1, NN / 64, 6), 256, 0, stream>>>(
      hM, hD, hT, 256, W1, inv_out, xs6, 256, 64, 0x543210);
  aggregate3<64><<<dim3(NN / 4, 3), 256, 0, stream>>>(
      xs6, csr, row_start, inv_in, b1, featA, E, 0x020100, nullptr);
  gemm64xs<<<dim3(1, NN / 64, 4), 256, 0, stream>>>(
      featA, featA + comp, featA + 2 * comp, 64, W2, inv_out, xs6, 64, 64, 0x5420);
  aggregate3<64><<<dim3(NN / 4, 2), 256, 0, stream>>>(
      xs6, csr, row_start, inv_in, b2, featB, E, 0x0201, nullptr);
  gemm64xs<<<dim3(2, NN / 64, 2), 256, 0, stream>>>(
      featB, featB + comp, featB + 2 * comp, 64, W3, inv_out, xs6, 64, 128, 0x31);
  aggregate3<128><<<dim3(4096 / 4, 1), 256, 0, stream>>>(
      xs6, csr, row_start, inv_in, b3, featA, E, 0x00, leftIndex);

  float* fake = (float*)d_out;                        // 4096 x 128 fp32
  float* outx = (float*)d_out + (size_t)4096 * 128;   // 4096 x 8192 fp32
  l1norm_fake<<<4096 / 4, 256, 0, stream>>>(featA, leftIndex, fake);

  // ---- weight cast+transpose, fused (after GNN: union region now safe) ----
  const int ncast = (8320 / 32) * (256 / 32) + (256 / 32) * (512 / 32) +
                    (512 / 32) * (1024 / 32) + (8192 / 32) * (1024 / 32);
  castT4<<<ncast, 256, 0, stream>>>(f1w, w1t, f2w, w2t, f3w, w3t, f4w, w4t);

  // ---- MLP (bf16 MFMA) ----
  mfma_gemm<1, 0><<<dim3(256 / 128, 4096 / 128, 8), 256, 0, stream>>>(
      nullptr, 0, Adj, fake, 8192, 8192, 128, w1t, 8320, nullptr,
      x1p, 256, 8320, 1056, 4096 * 256);
  reduceK<<<(4096 * 256 / 4 + 255) / 256, 256, 0, stream>>>(
      x1p, f1b, x1b, 4096 * 256, 256, 8, 4096 * 256);
  mfma_gemm<0, 1><<<dim3(512 / 128, 4096 / 128), 256, 0, stream>>>(
      x1b, 256, nullptr, nullptr, 0, 0, 0, w2t, 256, f2b, x2b, 512, 256, 256, 0);
  mfma_gemm<0, 1><<<dim3(1024 / 128, 4096 / 128), 256, 0, stream>>>(
      x2b, 512, nullptr, nullptr, 0, 0, 0, w3t, 512, f3b, x3b, 1024, 512, 512, 0);
  gemm256sig<<<512, 512, 0, stream>>>(x3b, 1024, w4t, 1024, f4b, outx, 8192);
}

// Round 16
// 414.925 us; speedup vs baseline: 1.3815x; 1.0658x over previous
//
#include <hip/hip_runtime.h>
#include <hip/hip_bf16.h>
#include <cstdint>
#include <cstddef>
#include <type_traits>

#define NN 8192
#define NTYPE 6
#define BPT 32  // histogram/scatter slices per (type, role)

typedef __attribute__((ext_vector_type(8))) short bf16x8;
typedef __attribute__((ext_vector_type(4))) float f32x4;
typedef __attribute__((ext_vector_type(4))) unsigned short u16x4;
typedef __attribute__((ext_vector_type(8))) unsigned short u16x8;

#define GLOAD16(g, l)                                                        \
  __builtin_amdgcn_global_load_lds(                                          \
      (const __attribute__((address_space(1))) void*)(g),                    \
      (__attribute__((address_space(3))) void*)(l), 16, 0, 0)

static __device__ __forceinline__ unsigned short f2bf(float f) {
  union { float f; unsigned u; } x; x.f = f;
  unsigned u = x.u + 0x7fffu + ((x.u >> 16) & 1u);
  return (unsigned short)(u >> 16);
}
static __device__ __forceinline__ float bf2f(unsigned short u) {
  union { unsigned u32; float f; } x; x.u32 = (unsigned)u << 16; return x.f;
}

// ---------------- degree histograms: LDS-privatized, non-atomic flush ----------------
__global__ __launch_bounds__(256) void hist_degree(
    const int* __restrict__ edges, int* __restrict__ partial, int E) {
  const int b = blockIdx.x, t = blockIdx.y, role = blockIdx.z;
  __shared__ int h[NN];
  for (int i = threadIdx.x; i < NN; i += 256) h[i] = 0;
  __syncthreads();
  const int* ids = edges + ((size_t)t * 2 + role) * E;
  int ch = (E + BPT - 1) / BPT;
  int beg = b * ch, end = (beg + ch < E) ? beg + ch : E;
  for (int i = beg + threadIdx.x; i < end; i += 256)
    atomicAdd(&h[__builtin_nontemporal_load(ids + i)], 1);
  __syncthreads();
  int* dst = partial + ((size_t)((role * NTYPE + t) * BPT + b)) * NN;
  for (int i = threadIdx.x; i < NN; i += 256) dst[i] = h[i];
}

// sum partials -> inv_out, inv_in, incnt (for scan)
__global__ __launch_bounds__(256) void reduce_deg(
    const int* __restrict__ partial, float* __restrict__ inv_out,
    float* __restrict__ inv_in, int* __restrict__ incnt) {
  int i = blockIdx.x * 256 + threadIdx.x;
  if (i >= NTYPE * NN) return;
  int t = i >> 13, n = i & (NN - 1);
  const int* ps = partial + ((size_t)(t * BPT)) * NN + n;
  const int* pd = partial + ((size_t)((NTYPE + t) * BPT)) * NN + n;
  int so = 0, sd = 0;
#pragma unroll 8
  for (int b = 0; b < BPT; ++b) { so += ps[(size_t)b * NN]; sd += pd[(size_t)b * NN]; }
  inv_out[i] = rsqrtf(fmaxf((float)so, 1.0f));
  inv_in[i]  = rsqrtf(fmaxf((float)sd, 1.0f));
  incnt[i]   = sd;
}

// one block per edge type: exclusive scan of indeg -> row_start
__global__ void scan_rows(const int* __restrict__ incnt, int* __restrict__ row_start) {
  int t = blockIdx.x;
  int i = threadIdx.x;
  const int* c = incnt + t * NN;
  int v[8], s = 0;
#pragma unroll
  for (int j = 0; j < 8; ++j) { v[j] = c[i * 8 + j]; s += v[j]; }
  __shared__ int p[1024];
  p[i] = s;
  __syncthreads();
  for (int d = 1; d < 1024; d <<= 1) {
    int x = (i >= d) ? p[i - d] : 0;
    __syncthreads();
    p[i] += x;
    __syncthreads();
  }
  int run = p[i] - s;
  int* rs = row_start + t * (NN + 1);
#pragma unroll
  for (int j = 0; j < 8; ++j) { rs[i * 8 + j] = run; run += v[j]; }
  if (i == 1023) rs[NN] = run;
}

// soff[t][s][d] = row_start[t][d] + sum_{s'<s} indeg_part[t][s'][d]
__global__ __launch_bounds__(256) void slice_offsets(
    const int* __restrict__ partial, const int* __restrict__ row_start,
    int* __restrict__ soff) {
  int i = blockIdx.x * 256 + threadIdx.x;
  if (i >= NTYPE * NN) return;
  int t = i >> 13, d = i & (NN - 1);
  const int* pd = partial + ((size_t)((NTYPE + t) * BPT)) * NN + d;
  int run = row_start[t * (NN + 1) + d];
  int* o = soff + ((size_t)t * BPT) * NN + d;
#pragma unroll 8
  for (int s = 0; s < BPT; ++s) { o[(size_t)s * NN] = run; run += pd[(size_t)s * NN]; }
}

// atomic-free scatter: LDS cursors seeded from soff; grid (8, BPT), x = type
__global__ __launch_bounds__(256) void scatter_v2(
    const int* __restrict__ edges, const int* __restrict__ soff,
    int* __restrict__ csr, int E) {
  int t = blockIdx.x;
  if (t >= NTYPE) return;
  int s = blockIdx.y;
  __shared__ int cur[NN];
  const int* o = soff + ((size_t)(t * BPT + s)) * NN;
  for (int i = threadIdx.x; i < NN; i += 256) cur[i] = o[i];
  __syncthreads();
  int ch = (E + BPT - 1) / BPT;
  int beg = s * ch, end = (beg + ch < E) ? beg + ch : E;
  const int* eb = edges + (size_t)t * 2 * E;
  int* out = csr + (size_t)t * E;
  for (int i = beg + threadIdx.x; i < end; i += 256) {
    int src = __builtin_nontemporal_load(eb + i);
    int dst = __builtin_nontemporal_load(eb + E + i);
    int pos = atomicAdd(&cur[dst], 1);
    out[pos] = src;
  }
}

// ---------------- batched 64x64 fp32 GEMM for GNN xs, bf16 out ----------------
// tpack: 4-bit packed list of active edge types, indexed by blockIdx.z.
__global__ __launch_bounds__(256) void gemm64xs(
    const float* __restrict__ p0, const float* __restrict__ p1,
    const float* __restrict__ p2, int lda,
    const float* __restrict__ WL, const float* __restrict__ inv_out,
    unsigned short* __restrict__ xs6, int F, int H, int tpack) {
  const int t = (tpack >> (4 * blockIdx.z)) & 15;
  const int srcc[6] = {0, 1, 0, 2, 2, 1};
  const float* A = (srcc[t] == 0) ? p0 : (srcc[t] == 1) ? p1 : p2;
  const float* B = WL + (size_t)t * F * H;  // (F,H) row-major, ldb=H
  const float* rscale = inv_out + t * NN;
  unsigned short* out = xs6 + (size_t)t * NN * H;

  __shared__ float As[16][68];
  __shared__ float Bs[16][68];
  int tid = threadIdx.x;
  int n0 = blockIdx.x * 64, m0 = blockIdx.y * 64;
  int ar = tid >> 2, ac = (tid & 3) * 4;
  int br = tid >> 4, bc = (tid & 15) * 4;
  int tx = tid & 15, ty = tid >> 4;
  float acc[4][4] = {};
  for (int k0 = 0; k0 < F; k0 += 16) {
    float4 av = *(const float4*)(A + (size_t)(m0 + ar) * lda + k0 + ac);
    As[ac + 0][ar] = av.x; As[ac + 1][ar] = av.y;
    As[ac + 2][ar] = av.z; As[ac + 3][ar] = av.w;
    *(float4*)&Bs[br][bc] = *(const float4*)(B + (size_t)(k0 + br) * H + n0 + bc);
    __syncthreads();
#pragma unroll
    for (int kk = 0; kk < 16; ++kk) {
      float4 a = *(const float4*)&As[kk][ty * 4];
      float4 b = *(const float4*)&Bs[kk][tx * 4];
      float aa[4] = {a.x, a.y, a.z, a.w};
      float bb[4] = {b.x, b.y, b.z, b.w};
#pragma unroll
      for (int i = 0; i < 4; ++i)
#pragma unroll
        for (int j = 0; j < 4; ++j) acc[i][j] += aa[i] * bb[j];
    }
    __syncthreads();
  }
#pragma unroll
  for (int i = 0; i < 4; ++i) {
    int r = m0 + ty * 4 + i;
    float sc = rscale[r];
    union { unsigned short us[4]; short4 v; } pk;
#pragma unroll
    for (int j = 0; j < 4; ++j) pk.us[j] = f2bf(acc[i][j] * sc);
    *(short4*)&out[(size_t)r * H + n0 + tx * 4] = pk.v;
  }
}

// ---------------- CSR aggregation v3: 4 edges/VMEM-instr vectorized gather ----
// cpack: 8-bit packed list of active target classes, indexed by blockIdx.y.
// dbase: optional device scalar added to the target-row index (dependency-cone
// prune: the final layer only needs rows [leftIndex, leftIndex+4096)).
template <int H>
__global__ __launch_bounds__(256) void aggregate3(
    const unsigned short* __restrict__ xs6, const int* __restrict__ csr,
    const int* __restrict__ row_start, const float* __restrict__ inv_in,
    const float* __restrict__ bL, float* __restrict__ feat_out, int E, int cpack,
    const int* __restrict__ dbase) {
  constexpr int VE = H / 16;
  const int c = (cpack >> (8 * blockIdx.y)) & 0xff;
  const int taT[3] = {1, 0, 2}, tbT[3] = {3, 4, 5};
  int wave = threadIdx.x >> 6, lane = threadIdx.x & 63;
  int slot = lane >> 4, colg = lane & 15;
  int d = blockIdx.x * 4 + wave;
  if (dbase) d += dbase[0];

  float out[VE];
#pragma unroll
  for (int v = 0; v < VE; ++v) out[v] = 0.f;

#pragma unroll
  for (int half = 0; half < 2; ++half) {
    int t = half ? tbT[c] : taT[c];
    const unsigned short* xs = xs6 + (size_t)t * NN * H;
    const int* cs = csr + (size_t)t * E;
    const int* rs = row_start + t * (NN + 1);
    int b = rs[d], e = rs[d + 1];
    float a[VE];
#pragma unroll
    for (int v = 0; v < VE; ++v) a[v] = 0.f;
    for (int j0 = b; j0 < e; j0 += 64) {
      int myj = j0 + lane;
      int idxv = (myj < e) ? cs[myj] : 0;
      int cnt = e - j0; if (cnt > 64) cnt = 64;
      int g = 0;
      for (; (g + 1) * 4 <= cnt; ++g) {
        int is = __shfl(idxv, g * 4 + slot);
        const unsigned short* xr = xs + (size_t)is * H + colg * VE;
        if constexpr (VE == 4) {
          u16x4 x = *(const u16x4*)xr;
#pragma unroll
          for (int v = 0; v < 4; ++v) a[v] += bf2f(x[v]);
        } else {
          u16x8 x = *(const u16x8*)xr;
#pragma unroll
          for (int v = 0; v < 8; ++v) a[v] += bf2f(x[v]);
        }
      }
      int done = g * 4;
      if (done < cnt) {
        int gi = done + slot;
        int is = __shfl(idxv, gi < cnt ? gi : 0);
        float wt = (gi < cnt) ? 1.0f : 0.0f;
        const unsigned short* xr = xs + (size_t)is * H + colg * VE;
        if constexpr (VE == 4) {
          u16x4 x = *(const u16x4*)xr;
#pragma unroll
          for (int v = 0; v < 4; ++v) a[v] += wt * bf2f(x[v]);
        } else {
          u16x8 x = *(const u16x8*)xr;
#pragma unroll
          for (int v = 0; v < 8; ++v) a[v] += wt * bf2f(x[v]);
        }
      }
    }
    float sc = inv_in[t * NN + d];
#pragma unroll
    for (int v = 0; v < VE; ++v) out[v] += a[v] * sc;
  }
#pragma unroll
  for (int v = 0; v < VE; ++v) {
    out[v] += __shfl_xor(out[v], 16);
    out[v] += __shfl_xor(out[v], 32);
  }
  if (lane < 16) {
    int ta = taT[c], tb = tbT[c];
    float* o = feat_out + (size_t)c * NN * 128 + (size_t)d * H + colg * VE;
    const float* ba = bL + ta * H + colg * VE;
    const float* bb = bL + tb * H + colg * VE;
    float4 w0 = make_float4(out[0] + ba[0] + bb[0], out[1] + ba[1] + bb[1],
                            out[2] + ba[2] + bb[2], out[3] + ba[3] + bb[3]);
    *(float4*)o = w0;
    if constexpr (VE == 8) {
      float4 w1 = make_float4(out[4] + ba[4] + bb[4], out[5] + ba[5] + bb[5],
                              out[6] + ba[6] + bb[6], out[7] + ba[7] + bb[7]);
      *(float4*)(o + 4) = w1;
    }
  }
}

// ---------------- row L1-normalize hM3 -> fake (fp32, to d_out) ----------------
__global__ __launch_bounds__(256) void l1norm_fake(
    const float* __restrict__ hM3, const int* __restrict__ leftIndex,
    float* __restrict__ fake) {
  int wave = threadIdx.x >> 6, lane = threadIdx.x & 63;
  int r = blockIdx.x * 4 + wave;
  int row = leftIndex[0] + r;
  const float* x = hM3 + (size_t)row * 128;
  float a = x[lane], b = x[64 + lane];
  float s = fabsf(a) + fabsf(b);
#pragma unroll
  for (int d = 1; d < 64; d <<= 1) s += __shfl_xor(s, d);
  float inv = 1.0f / fmaxf(s, 1e-12f);
  fake[(size_t)r * 128 + lane]      = a * inv;
  fake[(size_t)r * 128 + 64 + lane] = b * inv;
}

// ---------------- fused cast + transpose fp32 (K,N) -> bf16 (N,K), 4 weights ----
__global__ __launch_bounds__(256) void castT4(
    const float* __restrict__ i0, unsigned short* __restrict__ o0,
    const float* __restrict__ i1, unsigned short* __restrict__ o1,
    const float* __restrict__ i2, unsigned short* __restrict__ o2,
    const float* __restrict__ i3, unsigned short* __restrict__ o3) {
  // segments (K, N): (8320,256) (256,512) (512,1024) (1024,8192)
  const int nb0 = (8320 / 32) * (256 / 32);    // 2080
  const int nb1 = (256 / 32) * (512 / 32);     // 128
  const int nb2 = (512 / 32) * (1024 / 32);    // 512
  int b = blockIdx.x;
  const float* in; unsigned short* out; int K, N;
  if (b < nb0) { in = i0; out = o0; K = 8320; N = 256; }
  else if ((b -= nb0) < nb1) { in = i1; out = o1; K = 256; N = 512; }
  else if ((b -= nb1) < nb2) { in = i2; out = o2; K = 512; N = 1024; }
  else { b -= nb2; in = i3; out = o3; K = 1024; N = 8192; }
  int nx = N / 32;
  int n0 = (b % nx) * 32, k0 = (b / nx) * 32;

  __shared__ float t[32][33];
  int tx = threadIdx.x & 31, ty = threadIdx.x >> 5;  // 32x8
#pragma unroll
  for (int i = 0; i < 32; i += 8)
    t[ty + i][tx] = in[(size_t)(k0 + ty + i) * N + n0 + tx];
  __syncthreads();
#pragma unroll
  for (int i = 0; i < 32; i += 8)
    out[(size_t)(n0 + ty + i) * K + k0 + tx] = f2bf(t[tx][ty + i]);
}

// ---------------- bf16 MFMA GEMM, 128x128 tile, BK=32, swizzled LDS ----------
// ASRC: 0 = A bf16 (lda); 1 = A fp32 split (A1,K1,lda1 | A2,lda2), reg-staged cvt
//       (plain loads: A rows are reused across the 2 n-tiles, keep L2 reuse —
//        R15 lesson: NT loads here cost ~+26 µs).
// ACT:  0 = raw fp32 partial (split-K); 1 = relu -> bf16.
template <int ASRC, int ACT>
__global__ __launch_bounds__(256) void mfma_gemm(
    const unsigned short* __restrict__ Abf, int lda,
    const float* __restrict__ A1, const float* __restrict__ A2,
    int K1, int lda1, int lda2,
    const unsigned short* __restrict__ Bt, int ldb,
    const float* __restrict__ bias,
    void* __restrict__ outp, int ldo, int K, int kchunk, int pstride) {
  __shared__ unsigned short As[128 * 32];
  __shared__ unsigned short Bs[128 * 32];
  const int tid = threadIdx.x;
  const int n0 = blockIdx.x * 128, m0 = blockIdx.y * 128;
  const int wave = tid >> 6, lane = tid & 63;
  const int lq = lane >> 4, lr = lane & 15;
  const int wm = wave >> 1, wn = wave & 1;
  const int kbeg = blockIdx.z * kchunk;
  const int kend = (kbeg + kchunk < K) ? (kbeg + kchunk) : K;

  f32x4 acc[4][4] = {};

  const int G0 = tid, G1 = tid + 256;
  const int r0 = G0 >> 2, c0 = ((G0 & 3) - (r0 >> 1)) & 3;
  const int r1 = G1 >> 2, c1 = ((G1 & 3) - (r1 >> 1)) & 3;
  const int wbase0 = (tid & ~63) * 8;
  const int wbase1 = wbase0 + 256 * 8;

  for (int k0 = kbeg; k0 < kend; k0 += 32) {
    GLOAD16(Bt + (size_t)(n0 + r0) * ldb + k0 + c0 * 8, &Bs[wbase0]);
    GLOAD16(Bt + (size_t)(n0 + r1) * ldb + k0 + c1 * 8, &Bs[wbase1]);
    if (ASRC == 0) {
      GLOAD16(Abf + (size_t)(m0 + r0) * lda + k0 + c0 * 8, &As[wbase0]);
      GLOAD16(Abf + (size_t)(m0 + r1) * lda + k0 + c1 * 8, &As[wbase1]);
    } else {
#pragma unroll
      for (int q = 0; q < 2; ++q) {
        int r = q ? r1 : r0, c = q ? c1 : c0, G = q ? G1 : G0;
        int kk = k0 + c * 8;
        const float* src = (kk < K1) ? (A1 + (size_t)(m0 + r) * lda1 + kk)
                                     : (A2 + (size_t)(m0 + r) * lda2 + (kk - K1));
        float4 u = *(const float4*)src;
        float4 v = *(const float4*)(src + 4);
        union { unsigned short us[8]; bf16x8 v8; } pk;
        pk.us[0] = f2bf(u.x); pk.us[1] = f2bf(u.y);
        pk.us[2] = f2bf(u.z); pk.us[3] = f2bf(u.w);
        pk.us[4] = f2bf(v.x); pk.us[5] = f2bf(v.y);
        pk.us[6] = f2bf(v.z); pk.us[7] = f2bf(v.w);
        *(bf16x8*)&As[G * 8] = pk.v8;
      }
    }
    __syncthreads();

    const int cs = (lq + (lr >> 1)) & 3;
    const int rA = wm * 64 + lr, rB = wn * 64 + lr;
    bf16x8 af[4], bfr[4];
#pragma unroll
    for (int m = 0; m < 4; ++m)
      af[m] = *(const bf16x8*)&As[(((rA + m * 16) << 2) + cs) << 3];
#pragma unroll
    for (int n = 0; n < 4; ++n)
      bfr[n] = *(const bf16x8*)&Bs[(((rB + n * 16) << 2) + cs) << 3];
#pragma unroll
    for (int m = 0; m < 4; ++m)
#pragma unroll
      for (int n = 0; n < 4; ++n)
        acc[m][n] = __builtin_amdgcn_mfma_f32_16x16x32_bf16(af[m], bfr[n], acc[m][n], 0, 0, 0);
    __syncthreads();
  }

  const int rowb = m0 + wm * 64 + lq * 4;
  const int colb = n0 + wn * 64 + lr;
  float* pout = (ACT == 0) ? ((float*)outp + (size_t)blockIdx.z * pstride) : (float*)outp;
#pragma unroll
  for (int n = 0; n < 4; ++n) {
    int c = colb + n * 16;
    float bv = (ACT == 0) ? 0.0f : bias[c];
#pragma unroll
    for (int m = 0; m < 4; ++m) {
      int r = rowb + m * 16;
#pragma unroll
      for (int j = 0; j < 4; ++j) {
        float v = acc[m][n][j] + bv;
        if (ACT == 0) {
          pout[(size_t)(r + j) * ldo + c] = v;
        } else {
          v = fmaxf(v, 0.0f);
          ((unsigned short*)outp)[(size_t)(r + j) * ldo + c] = f2bf(v);
        }
      }
    }
  }
}

// ---------------- 256x256 reg-staged double-buffer bf16 MFMA GEMM + sigmoid ----
__global__ __launch_bounds__(512, 1) void gemm256sig(
    const unsigned short* __restrict__ A, int lda,
    const unsigned short* __restrict__ Bt, int ldb,
    const float* __restrict__ bias,
    float* __restrict__ out, int ldo) {
  __shared__ unsigned short sA[2][8192];  // [buf][256 rows x 32 k] swizzled
  __shared__ unsigned short sB[2][8192];
  const int tid = threadIdx.x;
  const int wave = tid >> 6, lane = tid & 63;
  const int lq = lane >> 4, lr = lane & 15;
  const int wm = wave >> 2, wn = wave & 3;
  // bijective XCD stripe swizzle: grid 512 = 8 xcd x (16 m x 4 n)
  const int bid = blockIdx.x;
  const int xcd = bid & 7, kb = bid >> 3;
  const int n0 = (xcd * 4 + (kb & 3)) * 256;
  const int m0 = (kb >> 2) * 256;

  f32x4 acc[8][4] = {};

  const int ra0 = tid >> 2, ca0 = tid & 3;
  const int ra1 = ra0 + 128, ca1 = ca0;
  const int sl0 = (ra0 << 2) + ((ca0 + (ra0 >> 1)) & 3);
  const int sl1 = (ra1 << 2) + ((ca1 + (ra1 >> 1)) & 3);

  u16x8 gA0, gA1, gB0, gB1;
  auto g_issue = [&](int h) {
    int kk = h * 32;
    gA0 = *(const u16x8*)(A  + (size_t)(m0 + ra0) * lda + kk + ca0 * 8);
    gA1 = *(const u16x8*)(A  + (size_t)(m0 + ra1) * lda + kk + ca1 * 8);
    gB0 = *(const u16x8*)(Bt + (size_t)(n0 + ra0) * ldb + kk + ca0 * 8);
    gB1 = *(const u16x8*)(Bt + (size_t)(n0 + ra1) * ldb + kk + ca1 * 8);
  };
  auto l_write = [&](int buf) {
    *(u16x8*)&sA[buf][sl0 * 8] = gA0;
    *(u16x8*)&sA[buf][sl1 * 8] = gA1;
    *(u16x8*)&sB[buf][sl0 * 8] = gB0;
    *(u16x8*)&sB[buf][sl1 * 8] = gB1;
  };

  g_issue(0);
  l_write(0);
  g_issue(1);
  __syncthreads();

#pragma unroll 1
  for (int h = 0; h < 32; ++h) {
    const int cur = h & 1, nxt = cur ^ 1;
    const unsigned short* pa = &sA[cur][0];
    const unsigned short* pb = &sB[cur][0];
    bf16x8 afv[8], bfv[4];
#pragma unroll
    for (int n = 0; n < 4; ++n) {
      int r = wn * 64 + n * 16 + lr;
      bfv[n] = *(const bf16x8*)&pb[(size_t)(((r << 2) + ((lq + (r >> 1)) & 3)) << 3)];
    }
#pragma unroll
    for (int m = 0; m < 8; ++m) {
      int r = wm * 128 + m * 16 + lr;
      afv[m] = *(const bf16x8*)&pa[(size_t)(((r << 2) + ((lq + (r >> 1)) & 3)) << 3)];
    }
    if (h + 1 < 32) l_write(nxt);
    if (h + 2 < 32) g_issue(h + 2);
    __builtin_amdgcn_s_setprio(1);
#pragma unroll
    for (int m = 0; m < 8; ++m)
#pragma unroll
      for (int n = 0; n < 4; ++n)
        acc[m][n] = __builtin_amdgcn_mfma_f32_16x16x32_bf16(afv[m], bfv[n], acc[m][n], 0, 0, 0);
    __builtin_amdgcn_s_setprio(0);
    __syncthreads();
  }

  // ---- epilogue: sigmoid + wave-private LDS transpose -> coalesced NT stores ----
  float* lw = (wave < 4) ? ((float*)&sA[0][0] + wave * 2048)
                         : ((float*)&sB[0][0] + (wave - 4) * 2048);
  const int rowb = m0 + wm * 128;
  const int colb = n0 + wn * 64;
  float bv[4];
#pragma unroll
  for (int n = 0; n < 4; ++n) bv[n] = bias[colb + n * 16 + lr];
#pragma unroll
  for (int m = 0; m < 8; ++m) {
#pragma unroll
    for (int n = 0; n < 4; ++n)
#pragma unroll
      for (int j = 0; j < 4; ++j) {
        float v = acc[m][n][j] + bv[n];
        v = 1.0f / (1.0f + __expf(-v));
        lw[(lq * 4 + j) * 68 + n * 16 + lr] = v;
      }
    asm volatile("s_waitcnt lgkmcnt(0)" ::: "memory");  // wave-private RAW
#pragma unroll
    for (int i = 0; i < 4; ++i) {
      int chunk = i * 64 + lane;             // 0..255: 16 rows x 16 chunks
      int rr = chunk >> 4, cg = chunk & 15;
      f32x4 val = *(f32x4*)&lw[rr * 68 + cg * 4];
      __builtin_nontemporal_store(
          val, (f32x4*)(out + (size_t)(rowb + m * 16 + rr) * ldo + colb + cg * 4));
    }
    asm volatile("s_waitcnt lgkmcnt(0)" ::: "memory");  // wave-private WAR
  }
}

// ---------------- split-K partial reduce + bias + relu -> bf16 ----------------
__global__ __launch_bounds__(256) void reduceK(
    const float* __restrict__ part, const float* __restrict__ bias,
    unsigned short* __restrict__ out, int total, int N, int nsplit, int pstride) {
  int idx = blockIdx.x * 256 + threadIdx.x;
  int base = idx * 4;
  if (base >= total) return;
  float4 s = *(const float4*)(part + base);
  for (int z = 1; z < nsplit; ++z) {
    float4 p = *(const float4*)(part + (size_t)z * pstride + base);
    s.x += p.x; s.y += p.y; s.z += p.z; s.w += p.w;
  }
  float4 bv = *(const float4*)(bias + (base & (N - 1)));
  union { unsigned short us[4]; short4 v; } pk;
  pk.us[0] = f2bf(fmaxf(s.x + bv.x, 0.0f));
  pk.us[1] = f2bf(fmaxf(s.y + bv.y, 0.0f));
  pk.us[2] = f2bf(fmaxf(s.z + bv.z, 0.0f));
  pk.us[3] = f2bf(fmaxf(s.w + bv.w, 0.0f));
  *(short4*)&out[base] = pk.v;
}

// ---------------- driver ----------------
extern "C" void kernel_launch(void* const* d_in, const int* in_sizes, int n_in,
                              void* d_out, int out_size, void* d_ws, size_t ws_size,
                              hipStream_t stream) {
  const float* hM  = (const float*)d_in[0];
  const float* hD  = (const float*)d_in[1];
  const float* hT  = (const float*)d_in[2];
  const float* W1  = (const float*)d_in[3];
  const float* b1  = (const float*)d_in[4];
  const float* W2  = (const float*)d_in[5];
  const float* b2  = (const float*)d_in[6];
  const float* W3  = (const float*)d_in[7];
  const float* b3  = (const float*)d_in[8];
  const float* Adj = (const float*)d_in[9];
  const float* f1w = (const float*)d_in[10];
  const float* f1b = (const float*)d_in[11];
  const float* f2w = (const float*)d_in[12];
  const float* f2b = (const float*)d_in[13];
  const float* f3w = (const float*)d_in[14];
  const float* f3b = (const float*)d_in[15];
  const float* f4w = (const float*)d_in[16];
  const float* f4b = (const float*)d_in[17];
  const int* edges = (const int*)d_in[18];
  const int* leftIndex = (const int*)d_in[20];
  const int E = in_sizes[18] / 12;  // 500000
  (void)ws_size; (void)n_in; (void)out_size;

  char* w = (char*)d_ws;
  size_t off = 0;
  auto alloc = [&](size_t bytes) {
    void* p = w + off;
    off = (off + bytes + 255) & ~(size_t)255;
    return p;
  };
  int*   row_start = (int*)  alloc((size_t)NTYPE * (NN + 1) * 4);
  int*   incnt     = (int*)  alloc((size_t)NTYPE * NN * 4);
  float* inv_out   = (float*)alloc((size_t)NTYPE * NN * 4);
  float* inv_in    = (float*)alloc((size_t)NTYPE * NN * 4);
  float* featA     = (float*)alloc((size_t)3 * NN * 128 * 4);   // persists to l1norm
  size_t ubase = off;  // ---- union region: GNN view ----
  int*            csr   = (int*)           alloc((size_t)NTYPE * E * 4);        // 12 MB
  unsigned short* xs6   = (unsigned short*)alloc((size_t)NTYPE * NN * 128 * 2); // 12.6 MB
  float*          featB = (float*)         alloc((size_t)3 * NN * 128 * 4);     // 12.6 MB
  int* deg_part = (int*)csr;            // aliases csr (dead until scatter)
  int* soff     = (int*)featB;          // aliases featB (dead until L=1)
  // ---- union region: MLP view (same bytes, GNN buffers dead) ----
  size_t moff = ubase;
  auto malloc2 = [&](size_t bytes) {
    void* p = w + moff;
    moff = (moff + bytes + 255) & ~(size_t)255;
    return p;
  };
  unsigned short* w1t = (unsigned short*)malloc2((size_t)256 * 8320 * 2);
  unsigned short* w2t = (unsigned short*)malloc2((size_t)512 * 256 * 2);
  unsigned short* w3t = (unsigned short*)malloc2((size_t)1024 * 512 * 2);
  unsigned short* w4t = (unsigned short*)malloc2((size_t)8192 * 1024 * 2);
  unsigned short* x1b = (unsigned short*)malloc2((size_t)4096 * 256 * 2);
  unsigned short* x2b = (unsigned short*)malloc2((size_t)4096 * 512 * 2);
  unsigned short* x3b = (unsigned short*)malloc2((size_t)4096 * 1024 * 2);
  float*          x1p = (float*)malloc2((size_t)8 * 4096 * 256 * 4);  // split-K x8 partials

  // ---- CSR build (no global atomics anywhere) ----
  hist_degree<<<dim3(BPT, NTYPE, 2), 256, 0, stream>>>(edges, deg_part, E);
  reduce_deg<<<(NTYPE * NN + 255) / 256, 256, 0, stream>>>(deg_part, inv_out, inv_in, incnt);
  scan_rows<<<NTYPE, 1024, 0, stream>>>(incnt, row_start);
  slice_offsets<<<(NTYPE * NN + 255) / 256, 256, 0, stream>>>(deg_part, row_start, soff);
  scatter_v2<<<dim3(8, BPT), 256, 0, stream>>>(edges, soff, csr, E);

  // ---- 3 GNN layers, dead-branch pruned ----
  // Only hM3[leftIndex : leftIndex+4096] is consumed downstream.
  const size_t comp = (size_t)NN * 128;
  gemm64xs<<<dim3(1, NN / 64, 6), 256, 0, stream>>>(
      hM, hD, hT, 256, W1, inv_out, xs6, 256, 64, 0x543210);
  aggregate3<64><<<dim3(NN / 4, 3), 256, 0, stream>>>(
      xs6, csr, row_start, inv_in, b1, featA, E, 0x020100, nullptr);
  gemm64xs<<<dim3(1, NN / 64, 4), 256, 0, stream>>>(
      featA, featA + comp, featA + 2 * comp, 64, W2, inv_out, xs6, 64, 64, 0x5420);
  aggregate3<64><<<dim3(NN / 4, 2), 256, 0, stream>>>(
      xs6, csr, row_start, inv_in, b2, featB, E, 0x0201, nullptr);
  gemm64xs<<<dim3(2, NN / 64, 2), 256, 0, stream>>>(
      featB, featB + comp, featB + 2 * comp, 64, W3, inv_out, xs6, 64, 128, 0x31);
  aggregate3<128><<<dim3(4096 / 4, 1), 256, 0, stream>>>(
      xs6, csr, row_start, inv_in, b3, featA, E, 0x00, leftIndex);

  float* fake = (float*)d_out;                        // 4096 x 128 fp32
  float* outx = (float*)d_out + (size_t)4096 * 128;   // 4096 x 8192 fp32
  l1norm_fake<<<4096 / 4, 256, 0, stream>>>(featA, leftIndex, fake);

  // ---- weight cast+transpose, fused (after GNN: union region now safe) ----
  const int ncast = (8320 / 32) * (256 / 32) + (256 / 32) * (512 / 32) +
                    (512 / 32) * (1024 / 32) + (8192 / 32) * (1024 / 32);
  castT4<<<ncast, 256, 0, stream>>>(f1w, w1t, f2w, w2t, f3w, w3t, f4w, w4t);

  // ---- MLP (bf16 MFMA) ----
  mfma_gemm<1, 0><<<dim3(256 / 128, 4096 / 128, 8), 256, 0, stream>>>(
      nullptr, 0, Adj, fake, 8192, 8192, 128, w1t, 8320, nullptr,
      x1p, 256, 8320, 1056, 4096 * 256);
  reduceK<<<(4096 * 256 / 4 + 255) / 256, 256, 0, stream>>>(
      x1p, f1b, x1b, 4096 * 256, 256, 8, 4096 * 256);
  mfma_gemm<0, 1><<<dim3(512 / 128, 4096 / 128), 256, 0, stream>>>(
      x1b, 256, nullptr, nullptr, 0, 0, 0, w2t, 256, f2b, x2b, 512, 256, 256, 0);
  mfma_gemm<0, 1><<<dim3(1024 / 128, 4096 / 128), 256, 0, stream>>>(
      x2b, 512, nullptr, nullptr, 0, 0, 0, w3t, 512, f3b, x3b, 1024, 512, 512, 0);
  gemm256sig<<<512, 512, 0, stream>>>(x3b, 1024, w4t, 1024, f4b, outx, 8192);
}

// Round 17
// 411.191 us; speedup vs baseline: 1.3941x; 1.0091x over previous
//
#include <hip/hip_runtime.h>
#include <hip/hip_bf16.h>
#include <cstdint>
#include <cstddef>
#include <type_traits>

#define NN 8192
#define NTYPE 6
#define BPT 32  // histogram/scatter slices per (type, role)

typedef __attribute__((ext_vector_type(8))) short bf16x8;
typedef __attribute__((ext_vector_type(4))) float f32x4;
typedef __attribute__((ext_vector_type(4))) unsigned short u16x4;
typedef __attribute__((ext_vector_type(8))) unsigned short u16x8;

#define GLOAD16(g, l)                                                        \
  __builtin_amdgcn_global_load_lds(                                          \
      (const __attribute__((address_space(1))) void*)(g),                    \
      (__attribute__((address_space(3))) void*)(l), 16, 0, 0)

static __device__ __forceinline__ unsigned short f2bf(float f) {
  union { float f; unsigned u; } x; x.f = f;
  unsigned u = x.u + 0x7fffu + ((x.u >> 16) & 1u);
  return (unsigned short)(u >> 16);
}
static __device__ __forceinline__ float bf2f(unsigned short u) {
  union { unsigned u32; float f; } x; x.u32 = (unsigned)u << 16; return x.f;
}

// ---------------- degree histograms: LDS-privatized, non-atomic flush ----------------
__global__ __launch_bounds__(256) void hist_degree(
    const int* __restrict__ edges, int* __restrict__ partial, int E) {
  const int b = blockIdx.x, t = blockIdx.y, role = blockIdx.z;
  __shared__ int h[NN];
  for (int i = threadIdx.x; i < NN; i += 256) h[i] = 0;
  __syncthreads();
  const int* ids = edges + ((size_t)t * 2 + role) * E;
  int ch = (E + BPT - 1) / BPT;
  int beg = b * ch, end = (beg + ch < E) ? beg + ch : E;
  for (int i = beg + threadIdx.x; i < end; i += 256)
    atomicAdd(&h[__builtin_nontemporal_load(ids + i)], 1);
  __syncthreads();
  int* dst = partial + ((size_t)((role * NTYPE + t) * BPT + b)) * NN;
  for (int i = threadIdx.x; i < NN; i += 256) dst[i] = h[i];
}

// sum partials -> inv_out, inv_in, incnt (for scan)
__global__ __launch_bounds__(256) void reduce_deg(
    const int* __restrict__ partial, float* __restrict__ inv_out,
    float* __restrict__ inv_in, int* __restrict__ incnt) {
  int i = blockIdx.x * 256 + threadIdx.x;
  if (i >= NTYPE * NN) return;
  int t = i >> 13, n = i & (NN - 1);
  const int* ps = partial + ((size_t)(t * BPT)) * NN + n;
  const int* pd = partial + ((size_t)((NTYPE + t) * BPT)) * NN + n;
  int so = 0, sd = 0;
#pragma unroll 8
  for (int b = 0; b < BPT; ++b) { so += ps[(size_t)b * NN]; sd += pd[(size_t)b * NN]; }
  inv_out[i] = rsqrtf(fmaxf((float)so, 1.0f));
  inv_in[i]  = rsqrtf(fmaxf((float)sd, 1.0f));
  incnt[i]   = sd;
}

// one block per edge type: exclusive scan of indeg -> row_start
__global__ void scan_rows(const int* __restrict__ incnt, int* __restrict__ row_start) {
  int t = blockIdx.x;
  int i = threadIdx.x;
  const int* c = incnt + t * NN;
  int v[8], s = 0;
#pragma unroll
  for (int j = 0; j < 8; ++j) { v[j] = c[i * 8 + j]; s += v[j]; }
  __shared__ int p[1024];
  p[i] = s;
  __syncthreads();
  for (int d = 1; d < 1024; d <<= 1) {
    int x = (i >= d) ? p[i - d] : 0;
    __syncthreads();
    p[i] += x;
    __syncthreads();
  }
  int run = p[i] - s;
  int* rs = row_start + t * (NN + 1);
#pragma unroll
  for (int j = 0; j < 8; ++j) { rs[i * 8 + j] = run; run += v[j]; }
  if (i == 1023) rs[NN] = run;
}

// soff[t][s][d] = row_start[t][d] + sum_{s'<s} indeg_part[t][s'][d]
__global__ __launch_bounds__(256) void slice_offsets(
    const int* __restrict__ partial, const int* __restrict__ row_start,
    int* __restrict__ soff) {
  int i = blockIdx.x * 256 + threadIdx.x;
  if (i >= NTYPE * NN) return;
  int t = i >> 13, d = i & (NN - 1);
  const int* pd = partial + ((size_t)((NTYPE + t) * BPT)) * NN + d;
  int run = row_start[t * (NN + 1) + d];
  int* o = soff + ((size_t)t * BPT) * NN + d;
#pragma unroll 8
  for (int s = 0; s < BPT; ++s) { o[(size_t)s * NN] = run; run += pd[(size_t)s * NN]; }
}

// atomic-free scatter: LDS cursors seeded from soff; grid (8, BPT), x = type
__global__ __launch_bounds__(256) void scatter_v2(
    const int* __restrict__ edges, const int* __restrict__ soff,
    int* __restrict__ csr, int E) {
  int t = blockIdx.x;
  if (t >= NTYPE) return;
  int s = blockIdx.y;
  __shared__ int cur[NN];
  const int* o = soff + ((size_t)(t * BPT + s)) * NN;
  for (int i = threadIdx.x; i < NN; i += 256) cur[i] = o[i];
  __syncthreads();
  int ch = (E + BPT - 1) / BPT;
  int beg = s * ch, end = (beg + ch < E) ? beg + ch : E;
  const int* eb = edges + (size_t)t * 2 * E;
  int* out = csr + (size_t)t * E;
  for (int i = beg + threadIdx.x; i < end; i += 256) {
    int src = __builtin_nontemporal_load(eb + i);
    int dst = __builtin_nontemporal_load(eb + E + i);
    int pos = atomicAdd(&cur[dst], 1);
    out[pos] = src;
  }
}

// ---------------- batched 64x64 fp32 GEMM for GNN xs, bf16 out ----------------
// tpack: 4-bit packed list of active edge types, indexed by blockIdx.z.
__global__ __launch_bounds__(256) void gemm64xs(
    const float* __restrict__ p0, const float* __restrict__ p1,
    const float* __restrict__ p2, int lda,
    const float* __restrict__ WL, const float* __restrict__ inv_out,
    unsigned short* __restrict__ xs6, int F, int H, int tpack) {
  const int t = (tpack >> (4 * blockIdx.z)) & 15;
  const int srcc[6] = {0, 1, 0, 2, 2, 1};
  const float* A = (srcc[t] == 0) ? p0 : (srcc[t] == 1) ? p1 : p2;
  const float* B = WL + (size_t)t * F * H;  // (F,H) row-major, ldb=H
  const float* rscale = inv_out + t * NN;
  unsigned short* out = xs6 + (size_t)t * NN * H;

  __shared__ float As[16][68];
  __shared__ float Bs[16][68];
  int tid = threadIdx.x;
  int n0 = blockIdx.x * 64, m0 = blockIdx.y * 64;
  int ar = tid >> 2, ac = (tid & 3) * 4;
  int br = tid >> 4, bc = (tid & 15) * 4;
  int tx = tid & 15, ty = tid >> 4;
  float acc[4][4] = {};
  for (int k0 = 0; k0 < F; k0 += 16) {
    float4 av = *(const float4*)(A + (size_t)(m0 + ar) * lda + k0 + ac);
    As[ac + 0][ar] = av.x; As[ac + 1][ar] = av.y;
    As[ac + 2][ar] = av.z; As[ac + 3][ar] = av.w;
    *(float4*)&Bs[br][bc] = *(const float4*)(B + (size_t)(k0 + br) * H + n0 + bc);
    __syncthreads();
#pragma unroll
    for (int kk = 0; kk < 16; ++kk) {
      float4 a = *(const float4*)&As[kk][ty * 4];
      float4 b = *(const float4*)&Bs[kk][tx * 4];
      float aa[4] = {a.x, a.y, a.z, a.w};
      float bb[4] = {b.x, b.y, b.z, b.w};
#pragma unroll
      for (int i = 0; i < 4; ++i)
#pragma unroll
        for (int j = 0; j < 4; ++j) acc[i][j] += aa[i] * bb[j];
    }
    __syncthreads();
  }
#pragma unroll
  for (int i = 0; i < 4; ++i) {
    int r = m0 + ty * 4 + i;
    float sc = rscale[r];
    union { unsigned short us[4]; short4 v; } pk;
#pragma unroll
    for (int j = 0; j < 4; ++j) pk.us[j] = f2bf(acc[i][j] * sc);
    *(short4*)&out[(size_t)r * H + n0 + tx * 4] = pk.v;
  }
}

// ---------------- CSR aggregation v3: 4 edges/VMEM-instr vectorized gather ----
// cpack: 8-bit packed list of active target classes, indexed by blockIdx.y.
// dbase: optional device scalar added to the target-row index (dependency-cone
// prune: the final layer only needs rows [leftIndex, leftIndex+4096)).
template <int H>
__global__ __launch_bounds__(256) void aggregate3(
    const unsigned short* __restrict__ xs6, const int* __restrict__ csr,
    const int* __restrict__ row_start, const float* __restrict__ inv_in,
    const float* __restrict__ bL, float* __restrict__ feat_out, int E, int cpack,
    const int* __restrict__ dbase) {
  constexpr int VE = H / 16;
  const int c = (cpack >> (8 * blockIdx.y)) & 0xff;
  const int taT[3] = {1, 0, 2}, tbT[3] = {3, 4, 5};
  int wave = threadIdx.x >> 6, lane = threadIdx.x & 63;
  int slot = lane >> 4, colg = lane & 15;
  int d = blockIdx.x * 4 + wave;
  if (dbase) d += dbase[0];

  float out[VE];
#pragma unroll
  for (int v = 0; v < VE; ++v) out[v] = 0.f;

#pragma unroll
  for (int half = 0; half < 2; ++half) {
    int t = half ? tbT[c] : taT[c];
    const unsigned short* xs = xs6 + (size_t)t * NN * H;
    const int* cs = csr + (size_t)t * E;
    const int* rs = row_start + t * (NN + 1);
    int b = rs[d], e = rs[d + 1];
    float a[VE];
#pragma unroll
    for (int v = 0; v < VE; ++v) a[v] = 0.f;
    for (int j0 = b; j0 < e; j0 += 64) {
      int myj = j0 + lane;
      int idxv = (myj < e) ? cs[myj] : 0;
      int cnt = e - j0; if (cnt > 64) cnt = 64;
      int g = 0;
      for (; (g + 1) * 4 <= cnt; ++g) {
        int is = __shfl(idxv, g * 4 + slot);
        const unsigned short* xr = xs + (size_t)is * H + colg * VE;
        if constexpr (VE == 4) {
          u16x4 x = *(const u16x4*)xr;
#pragma unroll
          for (int v = 0; v < 4; ++v) a[v] += bf2f(x[v]);
        } else {
          u16x8 x = *(const u16x8*)xr;
#pragma unroll
          for (int v = 0; v < 8; ++v) a[v] += bf2f(x[v]);
        }
      }
      int done = g * 4;
      if (done < cnt) {
        int gi = done + slot;
        int is = __shfl(idxv, gi < cnt ? gi : 0);
        float wt = (gi < cnt) ? 1.0f : 0.0f;
        const unsigned short* xr = xs + (size_t)is * H + colg * VE;
        if constexpr (VE == 4) {
          u16x4 x = *(const u16x4*)xr;
#pragma unroll
          for (int v = 0; v < 4; ++v) a[v] += wt * bf2f(x[v]);
        } else {
          u16x8 x = *(const u16x8*)xr;
#pragma unroll
          for (int v = 0; v < 8; ++v) a[v] += wt * bf2f(x[v]);
        }
      }
    }
    float sc = inv_in[t * NN + d];
#pragma unroll
    for (int v = 0; v < VE; ++v) out[v] += a[v] * sc;
  }
#pragma unroll
  for (int v = 0; v < VE; ++v) {
    out[v] += __shfl_xor(out[v], 16);
    out[v] += __shfl_xor(out[v], 32);
  }
  if (lane < 16) {
    int ta = taT[c], tb = tbT[c];
    float* o = feat_out + (size_t)c * NN * 128 + (size_t)d * H + colg * VE;
    const float* ba = bL + ta * H + colg * VE;
    const float* bb = bL + tb * H + colg * VE;
    float4 w0 = make_float4(out[0] + ba[0] + bb[0], out[1] + ba[1] + bb[1],
                            out[2] + ba[2] + bb[2], out[3] + ba[3] + bb[3]);
    *(float4*)o = w0;
    if constexpr (VE == 8) {
      float4 w1 = make_float4(out[4] + ba[4] + bb[4], out[5] + ba[5] + bb[5],
                              out[6] + ba[6] + bb[6], out[7] + ba[7] + bb[7]);
      *(float4*)(o + 4) = w1;
    }
  }
}

// ---------------- row L1-normalize hM3 -> fake (fp32, to d_out) ----------------
__global__ __launch_bounds__(256) void l1norm_fake(
    const float* __restrict__ hM3, const int* __restrict__ leftIndex,
    float* __restrict__ fake) {
  int wave = threadIdx.x >> 6, lane = threadIdx.x & 63;
  int r = blockIdx.x * 4 + wave;
  int row = leftIndex[0] + r;
  const float* x = hM3 + (size_t)row * 128;
  float a = x[lane], b = x[64 + lane];
  float s = fabsf(a) + fabsf(b);
#pragma unroll
  for (int d = 1; d < 64; d <<= 1) s += __shfl_xor(s, d);
  float inv = 1.0f / fmaxf(s, 1e-12f);
  fake[(size_t)r * 128 + lane]      = a * inv;
  fake[(size_t)r * 128 + 64 + lane] = b * inv;
}

// ---------------- fused cast + transpose fp32 (K,N) -> bf16 (N,K), 4 weights ----
__global__ __launch_bounds__(256) void castT4(
    const float* __restrict__ i0, unsigned short* __restrict__ o0,
    const float* __restrict__ i1, unsigned short* __restrict__ o1,
    const float* __restrict__ i2, unsigned short* __restrict__ o2,
    const float* __restrict__ i3, unsigned short* __restrict__ o3) {
  // segments (K, N): (8320,256) (256,512) (512,1024) (1024,8192)
  const int nb0 = (8320 / 32) * (256 / 32);    // 2080
  const int nb1 = (256 / 32) * (512 / 32);     // 128
  const int nb2 = (512 / 32) * (1024 / 32);    // 512
  int b = blockIdx.x;
  const float* in; unsigned short* out; int K, N;
  if (b < nb0) { in = i0; out = o0; K = 8320; N = 256; }
  else if ((b -= nb0) < nb1) { in = i1; out = o1; K = 256; N = 512; }
  else if ((b -= nb1) < nb2) { in = i2; out = o2; K = 512; N = 1024; }
  else { b -= nb2; in = i3; out = o3; K = 1024; N = 8192; }
  int nx = N / 32;
  int n0 = (b % nx) * 32, k0 = (b / nx) * 32;

  __shared__ float t[32][33];
  int tx = threadIdx.x & 31, ty = threadIdx.x >> 5;  // 32x8
#pragma unroll
  for (int i = 0; i < 32; i += 8)
    t[ty + i][tx] = in[(size_t)(k0 + ty + i) * N + n0 + tx];
  __syncthreads();
#pragma unroll
  for (int i = 0; i < 32; i += 8)
    out[(size_t)(n0 + ty + i) * K + k0 + tx] = f2bf(t[tx][ty + i]);
}

// ---------------- bf16 MFMA GEMM, 128x128 tile, BK=32, swizzled LDS ----------
// ASRC: 0 = A bf16 (lda); 1 = A fp32 split (A1,K1,lda1 | A2,lda2), reg-staged cvt
//       (plain loads keep L2 reuse across paired n-tiles — R15 lesson).
// ACT:  0 = raw fp32 partial (split-K); 1 = relu -> bf16.
// XYSWAP: 1 = blockIdx.x indexes m-tiles, .y indexes n-tiles. With grid
//       (M/128, N/128, z), the two n-tiles sharing an (m,z) A-slice are then
//       gridDim.x (=32 for L1) apart in dispatch order — a multiple of 8, so
//       both land on the SAME XCD and share the A k-slice in its L2
//       (default linearization puts them 1 apart -> different XCDs).
template <int ASRC, int ACT, int XYSWAP = 0>
__global__ __launch_bounds__(256) void mfma_gemm(
    const unsigned short* __restrict__ Abf, int lda,
    const float* __restrict__ A1, const float* __restrict__ A2,
    int K1, int lda1, int lda2,
    const unsigned short* __restrict__ Bt, int ldb,
    const float* __restrict__ bias,
    void* __restrict__ outp, int ldo, int K, int kchunk, int pstride) {
  __shared__ unsigned short As[128 * 32];
  __shared__ unsigned short Bs[128 * 32];
  const int tid = threadIdx.x;
  const int n0 = (XYSWAP ? blockIdx.y : blockIdx.x) * 128;
  const int m0 = (XYSWAP ? blockIdx.x : blockIdx.y) * 128;
  const int wave = tid >> 6, lane = tid & 63;
  const int lq = lane >> 4, lr = lane & 15;
  const int wm = wave >> 1, wn = wave & 1;
  const int kbeg = blockIdx.z * kchunk;
  const int kend = (kbeg + kchunk < K) ? (kbeg + kchunk) : K;

  f32x4 acc[4][4] = {};

  const int G0 = tid, G1 = tid + 256;
  const int r0 = G0 >> 2, c0 = ((G0 & 3) - (r0 >> 1)) & 3;
  const int r1 = G1 >> 2, c1 = ((G1 & 3) - (r1 >> 1)) & 3;
  const int wbase0 = (tid & ~63) * 8;
  const int wbase1 = wbase0 + 256 * 8;

  for (int k0 = kbeg; k0 < kend; k0 += 32) {
    GLOAD16(Bt + (size_t)(n0 + r0) * ldb + k0 + c0 * 8, &Bs[wbase0]);
    GLOAD16(Bt + (size_t)(n0 + r1) * ldb + k0 + c1 * 8, &Bs[wbase1]);
    if (ASRC == 0) {
      GLOAD16(Abf + (size_t)(m0 + r0) * lda + k0 + c0 * 8, &As[wbase0]);
      GLOAD16(Abf + (size_t)(m0 + r1) * lda + k0 + c1 * 8, &As[wbase1]);
    } else {
#pragma unroll
      for (int q = 0; q < 2; ++q) {
        int r = q ? r1 : r0, c = q ? c1 : c0, G = q ? G1 : G0;
        int kk = k0 + c * 8;
        const float* src = (kk < K1) ? (A1 + (size_t)(m0 + r) * lda1 + kk)
                                     : (A2 + (size_t)(m0 + r) * lda2 + (kk - K1));
        float4 u = *(const float4*)src;
        float4 v = *(const float4*)(src + 4);
        union { unsigned short us[8]; bf16x8 v8; } pk;
        pk.us[0] = f2bf(u.x); pk.us[1] = f2bf(u.y);
        pk.us[2] = f2bf(u.z); pk.us[3] = f2bf(u.w);
        pk.us[4] = f2bf(v.x); pk.us[5] = f2bf(v.y);
        pk.us[6] = f2bf(v.z); pk.us[7] = f2bf(v.w);
        *(bf16x8*)&As[G * 8] = pk.v8;
      }
    }
    __syncthreads();

    const int cs = (lq + (lr >> 1)) & 3;
    const int rA = wm * 64 + lr, rB = wn * 64 + lr;
    bf16x8 af[4], bfr[4];
#pragma unroll
    for (int m = 0; m < 4; ++m)
      af[m] = *(const bf16x8*)&As[(((rA + m * 16) << 2) + cs) << 3];
#pragma unroll
    for (int n = 0; n < 4; ++n)
      bfr[n] = *(const bf16x8*)&Bs[(((rB + n * 16) << 2) + cs) << 3];
#pragma unroll
    for (int m = 0; m < 4; ++m)
#pragma unroll
      for (int n = 0; n < 4; ++n)
        acc[m][n] = __builtin_amdgcn_mfma_f32_16x16x32_bf16(af[m], bfr[n], acc[m][n], 0, 0, 0);
    __syncthreads();
  }

  const int rowb = m0 + wm * 64 + lq * 4;
  const int colb = n0 + wn * 64 + lr;
  float* pout = (ACT == 0) ? ((float*)outp + (size_t)blockIdx.z * pstride) : (float*)outp;
#pragma unroll
  for (int n = 0; n < 4; ++n) {
    int c = colb + n * 16;
    float bv = (ACT == 0) ? 0.0f : bias[c];
#pragma unroll
    for (int m = 0; m < 4; ++m) {
      int r = rowb + m * 16;
#pragma unroll
      for (int j = 0; j < 4; ++j) {
        float v = acc[m][n][j] + bv;
        if (ACT == 0) {
          pout[(size_t)(r + j) * ldo + c] = v;
        } else {
          v = fmaxf(v, 0.0f);
          ((unsigned short*)outp)[(size_t)(r + j) * ldo + c] = f2bf(v);
        }
      }
    }
  }
}

// ---------------- 256x256 reg-staged double-buffer bf16 MFMA GEMM + sigmoid ----
__global__ __launch_bounds__(512, 1) void gemm256sig(
    const unsigned short* __restrict__ A, int lda,
    const unsigned short* __restrict__ Bt, int ldb,
    const float* __restrict__ bias,
    float* __restrict__ out, int ldo) {
  __shared__ unsigned short sA[2][8192];  // [buf][256 rows x 32 k] swizzled
  __shared__ unsigned short sB[2][8192];
  const int tid = threadIdx.x;
  const int wave = tid >> 6, lane = tid & 63;
  const int lq = lane >> 4, lr = lane & 15;
  const int wm = wave >> 2, wn = wave & 3;
  // bijective XCD stripe swizzle: grid 512 = 8 xcd x (16 m x 4 n)
  const int bid = blockIdx.x;
  const int xcd = bid & 7, kb = bid >> 3;
  const int n0 = (xcd * 4 + (kb & 3)) * 256;
  const int m0 = (kb >> 2) * 256;

  f32x4 acc[8][4] = {};

  const int ra0 = tid >> 2, ca0 = tid & 3;
  const int ra1 = ra0 + 128, ca1 = ca0;
  const int sl0 = (ra0 << 2) + ((ca0 + (ra0 >> 1)) & 3);
  const int sl1 = (ra1 << 2) + ((ca1 + (ra1 >> 1)) & 3);

  u16x8 gA0, gA1, gB0, gB1;
  auto g_issue = [&](int h) {
    int kk = h * 32;
    gA0 = *(const u16x8*)(A  + (size_t)(m0 + ra0) * lda + kk + ca0 * 8);
    gA1 = *(const u16x8*)(A  + (size_t)(m0 + ra1) * lda + kk + ca1 * 8);
    gB0 = *(const u16x8*)(Bt + (size_t)(n0 + ra0) * ldb + kk + ca0 * 8);
    gB1 = *(const u16x8*)(Bt + (size_t)(n0 + ra1) * ldb + kk + ca1 * 8);
  };
  auto l_write = [&](int buf) {
    *(u16x8*)&sA[buf][sl0 * 8] = gA0;
    *(u16x8*)&sA[buf][sl1 * 8] = gA1;
    *(u16x8*)&sB[buf][sl0 * 8] = gB0;
    *(u16x8*)&sB[buf][sl1 * 8] = gB1;
  };

  g_issue(0);
  l_write(0);
  g_issue(1);
  __syncthreads();

#pragma unroll 1
  for (int h = 0; h < 32; ++h) {
    const int cur = h & 1, nxt = cur ^ 1;
    const unsigned short* pa = &sA[cur][0];
    const unsigned short* pb = &sB[cur][0];
    bf16x8 afv[8], bfv[4];
#pragma unroll
    for (int n = 0; n < 4; ++n) {
      int r = wn * 64 + n * 16 + lr;
      bfv[n] = *(const bf16x8*)&pb[(size_t)(((r << 2) + ((lq + (r >> 1)) & 3)) << 3)];
    }
#pragma unroll
    for (int m = 0; m < 8; ++m) {
      int r = wm * 128 + m * 16 + lr;
      afv[m] = *(const bf16x8*)&pa[(size_t)(((r << 2) + ((lq + (r >> 1)) & 3)) << 3)];
    }
    if (h + 1 < 32) l_write(nxt);
    if (h + 2 < 32) g_issue(h + 2);
    __builtin_amdgcn_s_setprio(1);
#pragma unroll
    for (int m = 0; m < 8; ++m)
#pragma unroll
      for (int n = 0; n < 4; ++n)
        acc[m][n] = __builtin_amdgcn_mfma_f32_16x16x32_bf16(afv[m], bfv[n], acc[m][n], 0, 0, 0);
    __builtin_amdgcn_s_setprio(0);
    __syncthreads();
  }

  // ---- epilogue: sigmoid + wave-private LDS transpose -> coalesced NT stores ----
  float* lw = (wave < 4) ? ((float*)&sA[0][0] + wave * 2048)
                         : ((float*)&sB[0][0] + (wave - 4) * 2048);
  const int rowb = m0 + wm * 128;
  const int colb = n0 + wn * 64;
  float bv[4];
#pragma unroll
  for (int n = 0; n < 4; ++n) bv[n] = bias[colb + n * 16 + lr];
#pragma unroll
  for (int m = 0; m < 8; ++m) {
#pragma unroll
    for (int n = 0; n < 4; ++n)
#pragma unroll
      for (int j = 0; j < 4; ++j) {
        float v = acc[m][n][j] + bv[n];
        v = 1.0f / (1.0f + __expf(-v));
        lw[(lq * 4 + j) * 68 + n * 16 + lr] = v;
      }
    asm volatile("s_waitcnt lgkmcnt(0)" ::: "memory");  // wave-private RAW
#pragma unroll
    for (int i = 0; i < 4; ++i) {
      int chunk = i * 64 + lane;             // 0..255: 16 rows x 16 chunks
      int rr = chunk >> 4, cg = chunk & 15;
      f32x4 val = *(f32x4*)&lw[rr * 68 + cg * 4];
      __builtin_nontemporal_store(
          val, (f32x4*)(out + (size_t)(rowb + m * 16 + rr) * ldo + colb + cg * 4));
    }
    asm volatile("s_waitcnt lgkmcnt(0)" ::: "memory");  // wave-private WAR
  }
}

// ---------------- split-K partial reduce + bias + relu -> bf16 ----------------
__global__ __launch_bounds__(256) void reduceK(
    const float* __restrict__ part, const float* __restrict__ bias,
    unsigned short* __restrict__ out, int total, int N, int nsplit, int pstride) {
  int idx = blockIdx.x * 256 + threadIdx.x;
  int base = idx * 4;
  if (base >= total) return;
  float4 s = *(const float4*)(part + base);
  for (int z = 1; z < nsplit; ++z) {
    float4 p = *(const float4*)(part + (size_t)z * pstride + base);
    s.x += p.x; s.y += p.y; s.z += p.z; s.w += p.w;
  }
  float4 bv = *(const float4*)(bias + (base & (N - 1)));
  union { unsigned short us[4]; short4 v; } pk;
  pk.us[0] = f2bf(fmaxf(s.x + bv.x, 0.0f));
  pk.us[1] = f2bf(fmaxf(s.y + bv.y, 0.0f));
  pk.us[2] = f2bf(fmaxf(s.z + bv.z, 0.0f));
  pk.us[3] = f2bf(fmaxf(s.w + bv.w, 0.0f));
  *(short4*)&out[base] = pk.v;
}

// ---------------- driver ----------------
extern "C" void kernel_launch(void* const* d_in, const int* in_sizes, int n_in,
                              void* d_out, int out_size, void* d_ws, size_t ws_size,
                              hipStream_t stream) {
  const float* hM  = (const float*)d_in[0];
  const float* hD  = (const float*)d_in[1];
  const float* hT  = (const float*)d_in[2];
  const float* W1  = (const float*)d_in[3];
  const float* b1  = (const float*)d_in[4];
  const float* W2  = (const float*)d_in[5];
  const float* b2  = (const float*)d_in[6];
  const float* W3  = (const float*)d_in[7];
  const float* b3  = (const float*)d_in[8];
  const float* Adj = (const float*)d_in[9];
  const float* f1w = (const float*)d_in[10];
  const float* f1b = (const float*)d_in[11];
  const float* f2w = (const float*)d_in[12];
  const float* f2b = (const float*)d_in[13];
  const float* f3w = (const float*)d_in[14];
  const float* f3b = (const float*)d_in[15];
  const float* f4w = (const float*)d_in[16];
  const float* f4b = (const float*)d_in[17];
  const int* edges = (const int*)d_in[18];
  const int* leftIndex = (const int*)d_in[20];
  const int E = in_sizes[18] / 12;  // 500000
  (void)ws_size; (void)n_in; (void)out_size;

  char* w = (char*)d_ws;
  size_t off = 0;
  auto alloc = [&](size_t bytes) {
    void* p = w + off;
    off = (off + bytes + 255) & ~(size_t)255;
    return p;
  };
  int*   row_start = (int*)  alloc((size_t)NTYPE * (NN + 1) * 4);
  int*   incnt     = (int*)  alloc((size_t)NTYPE * NN * 4);
  float* inv_out   = (float*)alloc((size_t)NTYPE * NN * 4);
  float* inv_in    = (float*)alloc((size_t)NTYPE * NN * 4);
  float* featA     = (float*)alloc((size_t)3 * NN * 128 * 4);   // persists to l1norm
  size_t ubase = off;  // ---- union region: GNN view ----
  int*            csr   = (int*)           alloc((size_t)NTYPE * E * 4);        // 12 MB
  unsigned short* xs6   = (unsigned short*)alloc((size_t)NTYPE * NN * 128 * 2); // 12.6 MB
  float*          featB = (float*)         alloc((size_t)3 * NN * 128 * 4);     // 12.6 MB
  int* deg_part = (int*)csr;            // aliases csr (dead until scatter)
  int* soff     = (int*)featB;          // aliases featB (dead until L=1)
  // ---- union region: MLP view (same bytes, GNN buffers dead) ----
  size_t moff = ubase;
  auto malloc2 = [&](size_t bytes) {
    void* p = w + moff;
    moff = (moff + bytes + 255) & ~(size_t)255;
    return p;
  };
  unsigned short* w1t = (unsigned short*)malloc2((size_t)256 * 8320 * 2);
  unsigned short* w2t = (unsigned short*)malloc2((size_t)512 * 256 * 2);
  unsigned short* w3t = (unsigned short*)malloc2((size_t)1024 * 512 * 2);
  unsigned short* w4t = (unsigned short*)malloc2((size_t)8192 * 1024 * 2);
  unsigned short* x1b = (unsigned short*)malloc2((size_t)4096 * 256 * 2);
  unsigned short* x2b = (unsigned short*)malloc2((size_t)4096 * 512 * 2);
  unsigned short* x3b = (unsigned short*)malloc2((size_t)4096 * 1024 * 2);
  float*          x1p = (float*)malloc2((size_t)8 * 4096 * 256 * 4);  // split-K x8 partials

  // ---- CSR build (no global atomics anywhere) ----
  hist_degree<<<dim3(BPT, NTYPE, 2), 256, 0, stream>>>(edges, deg_part, E);
  reduce_deg<<<(NTYPE * NN + 255) / 256, 256, 0, stream>>>(deg_part, inv_out, inv_in, incnt);
  scan_rows<<<NTYPE, 1024, 0, stream>>>(incnt, row_start);
  slice_offsets<<<(NTYPE * NN + 255) / 256, 256, 0, stream>>>(deg_part, row_start, soff);
  scatter_v2<<<dim3(8, BPT), 256, 0, stream>>>(edges, soff, csr, E);

  // ---- 3 GNN layers, dead-branch pruned ----
  // Only hM3[leftIndex : leftIndex+4096] is consumed downstream.
  const size_t comp = (size_t)NN * 128;
  gemm64xs<<<dim3(1, NN / 64, 6), 256, 0, stream>>>(
      hM, hD, hT, 256, W1, inv_out, xs6, 256, 64, 0x543210);
  aggregate3<64><<<dim3(NN / 4, 3), 256, 0, stream>>>(
      xs6, csr, row_start, inv_in, b1, featA, E, 0x020100, nullptr);
  gemm64xs<<<dim3(1, NN / 64, 4), 256, 0, stream>>>(
      featA, featA + comp, featA + 2 * comp, 64, W2, inv_out, xs6, 64, 64, 0x5420);
  aggregate3<64><<<dim3(NN / 4, 2), 256, 0, stream>>>(
      xs6, csr, row_start, inv_in, b2, featB, E, 0x0201, nullptr);
  gemm64xs<<<dim3(2, NN / 64, 2), 256, 0, stream>>>(
      featB, featB + comp, featB + 2 * comp, 64, W3, inv_out, xs6, 64, 128, 0x31);
  aggregate3<128><<<dim3(4096 / 4, 1), 256, 0, stream>>>(
      xs6, csr, row_start, inv_in, b3, featA, E, 0x00, leftIndex);

  float* fake = (float*)d_out;                        // 4096 x 128 fp32
  float* outx = (float*)d_out + (size_t)4096 * 128;   // 4096 x 8192 fp32
  l1norm_fake<<<4096 / 4, 256, 0, stream>>>(featA, leftIndex, fake);

  // ---- weight cast+transpose, fused (after GNN: union region now safe) ----
  const int ncast = (8320 / 32) * (256 / 32) + (256 / 32) * (512 / 32) +
                    (512 / 32) * (1024 / 32) + (8192 / 32) * (1024 / 32);
  castT4<<<ncast, 256, 0, stream>>>(f1w, w1t, f2w, w2t, f3w, w3t, f4w, w4t);

  // ---- MLP (bf16 MFMA) ----
  // L1: XYSWAP grid (m=32, n=2, z=8) so paired n-tiles share an XCD L2 A-slice.
  mfma_gemm<1, 0, 1><<<dim3(4096 / 128, 256 / 128, 8), 256, 0, stream>>>(
      nullptr, 0, Adj, fake, 8192, 8192, 128, w1t, 8320, nullptr,
      x1p, 256, 8320, 1056, 4096 * 256);
  reduceK<<<(4096 * 256 / 4 + 255) / 256, 256, 0, stream>>>(
      x1p, f1b, x1b, 4096 * 256, 256, 8, 4096 * 256);
  mfma_gemm<0, 1><<<dim3(512 / 128, 4096 / 128), 256, 0, stream>>>(
      x1b, 256, nullptr, nullptr, 0, 0, 0, w2t, 256, f2b, x2b, 512, 256, 256, 0);
  mfma_gemm<0, 1><<<dim3(1024 / 128, 4096 / 128), 256, 0, stream>>>(
      x2b, 512, nullptr, nullptr, 0, 0, 0, w3t, 512, f3b, x3b, 1024, 512, 512, 0);
  gemm256sig<<<512, 512, 0, stream>>>(x3b, 1024, w4t, 1024, f4b, outx, 8192);
}